// Round 5
// baseline (1155.017 us; speedup 1.0000x reference)
//
#include <hip/hip_runtime.h>
#include <hip/hip_bf16.h>

using bf16 = __hip_bfloat16;
typedef __attribute__((ext_vector_type(8))) short short8;
typedef __attribute__((ext_vector_type(4))) float floatx4;

#define QLEN 1024
#define KLEN 1024
#define RLEN 2048
#define RUSED 1152   /* kr rows actually referenced by attention: t in [1,1088] */
#define BB   4
#define DMODEL 1024
#define NH   16
#define DH   64
#define DI   4096
#define ND   1024
#define QKVS 3072   /* fused qkv row stride */
#define SCALE 0.125f

// async global->LDS, 16B per lane, wave-uniform LDS base + lane*16 layout
__device__ inline void gl_lds16(const bf16* g, bf16* l) {
  __builtin_amdgcn_global_load_lds(
      (__attribute__((address_space(1))) void*)(g),
      (__attribute__((address_space(3))) void*)(l), 16, 0, 0);
}

// ---------------------------------------------------------------------------
// Fused f32->bf16 converts for h | r(first RUSED rows) | o_w (flat decode).
// ---------------------------------------------------------------------------
__global__ __launch_bounds__(256) void cvt_all(
    const float* __restrict__ h, const float* __restrict__ r,
    const float* __restrict__ ow,
    bf16* __restrict__ hb, bf16* __restrict__ rb, bf16* __restrict__ wo)
{
  const int id = blockIdx.x;
  const float* src; bf16* dst; int off;
  if (id < 2048)      { src = h;  dst = hb; off = id * 2048; }
  else if (id < 4352) { src = r;  dst = rb; off = (id - 2048) * 2048; }
  else                { src = ow; dst = wo; off = (id - 4352) * 2048; }
  const int idx = off + threadIdx.x * 8;
  const float4 a = *reinterpret_cast<const float4*>(src + idx);
  const float4 b = *reinterpret_cast<const float4*>(src + idx + 4);
  bf16 o[8] = {__float2bfloat16(a.x), __float2bfloat16(a.y),
               __float2bfloat16(a.z), __float2bfloat16(a.w),
               __float2bfloat16(b.x), __float2bfloat16(b.y),
               __float2bfloat16(b.z), __float2bfloat16(b.w)};
  *reinterpret_cast<uint4*>(dst + idx) = *reinterpret_cast<uint4*>(o);
}

// ---------------------------------------------------------------------------
// Fused transpose+convert for q_w|k_w|v_w|r_w|ff_w1|ff_w2 (flat decode).
// ---------------------------------------------------------------------------
__device__ inline void tconv_tile(const float* __restrict__ src, bf16* __restrict__ dst,
                                  int R, int C, int bx, int by, int tid) {
  __shared__ float tile[32][33];
  const int r0 = by * 32, c0 = bx * 32;
  {
    const int tr = tid >> 3, tc = (tid & 7) * 4;
    const float4 f = *reinterpret_cast<const float4*>(src + (size_t)(r0 + tr) * C + c0 + tc);
    tile[tr][tc + 0] = f.x; tile[tr][tc + 1] = f.y;
    tile[tr][tc + 2] = f.z; tile[tr][tc + 3] = f.w;
  }
  __syncthreads();
  {
    const int oc = tid >> 3, orr = (tid & 7) * 4;
    bf16 o[4];
#pragma unroll
    for (int u = 0; u < 4; ++u) o[u] = __float2bfloat16(tile[orr + u][oc]);
    *reinterpret_cast<uint2*>(dst + (size_t)(c0 + oc) * R + r0 + orr) = *reinterpret_cast<uint2*>(o);
  }
}

__global__ __launch_bounds__(256) void tconv_all(
    const float* __restrict__ qw, const float* __restrict__ kw,
    const float* __restrict__ vw, const float* __restrict__ rw,
    const float* __restrict__ w1, const float* __restrict__ w2,
    bf16* __restrict__ wqkvt, bf16* __restrict__ wrt,
    bf16* __restrict__ w1t, bf16* __restrict__ w2t)
{
  const int id = blockIdx.x;
  const int tid = threadIdx.x;
  if (id < 4096) {
    const int part = id >> 10, local = id & 1023;
    const float* src = (part == 0) ? qw : (part == 1) ? kw : (part == 2) ? vw : rw;
    bf16* dst = (part < 3) ? (wqkvt + (size_t)part * ND * DMODEL) : wrt;
    tconv_tile(src, dst, DMODEL, ND, local & 31, local >> 5, tid);
  } else if (id < 8192) {
    const int local = id - 4096;
    tconv_tile(w1, w1t, DMODEL, DI, local & 127, local >> 7, tid);
  } else {
    const int local = id - 8192;
    tconv_tile(w2, w2t, DI, DMODEL, local & 31, local >> 5, tid);
  }
}

// ---------------------------------------------------------------------------
// seg_mat one-hot collapse: ds[b][i] = seg_mat[i, 0, b, 1]  (s_i XOR s_0).
// ---------------------------------------------------------------------------
__global__ __launch_bounds__(256) void seg_extract(const float* __restrict__ seg,
                                                   float* __restrict__ dsb) {
  const int idx = blockIdx.x * 256 + threadIdx.x;   // 4096
  const int i = idx >> 2, b = idx & 3;
  dsb[b * QLEN + i] = seg[(size_t)(i * KLEN * BB + b) * 2 + 1];
}

// ---------------------------------------------------------------------------
// MFMA bf16 GEMM: C[M,N] = A[M,Ktot] @ Bt[N,Ktot]^T, f32 accum.
// 128x128 tile, BK=32 (kept for kr / o-proj shapes).
// ---------------------------------------------------------------------------
__global__ __launch_bounds__(256) void gemm_bt(
    const bf16* __restrict__ A, const bf16* __restrict__ Bt,
    int M, int N, int K, int Ktot, int lda, int ldb,
    const float* __restrict__ bias, const float* __restrict__ resid, int act_gelu,
    float* __restrict__ outf, bf16* __restrict__ outb, int pstride)
{
  __shared__ bf16 As[128][32];
  __shared__ bf16 Bs[128][32];

  const int tid = threadIdx.x;
  const int m0b = blockIdx.y * 128;
  const int n0b = blockIdx.x * 128;
  const int z = blockIdx.z;
  const int kbeg = z * K;
  const int kcnt = min(K, Ktot - kbeg);
  A  += (size_t)kbeg;
  Bt += (size_t)kbeg;
  float* of = outf ? (outf + (size_t)z * pstride) : outf;
  bf16*  ob = outb ? (outb + (size_t)z * pstride) : outb;

  const int wave = tid >> 6, lane = tid & 63;
  const int wm = (wave & 1) * 64, wn = (wave >> 1) * 64;
  const int fl = lane & 15, quad = lane >> 4;

  const int lr = lane >> 2;                              // 0..15
  const int cg = (((lane & 3) ^ ((lr >> 1) & 3)) << 3);  // swizzled global chunk (elems)
  const bf16* ga0 = A  + (size_t)(m0b + wave * 32 + lr) * lda + cg;
  const bf16* ga1 = ga0 + (size_t)16 * lda;
  const bf16* gb0 = Bt + (size_t)(n0b + wave * 32 + lr) * ldb + cg;
  const bf16* gb1 = gb0 + (size_t)16 * ldb;
  bf16* la0 = &As[wave * 32 + lr][(lane & 3) * 8];
  bf16* la1 = &As[wave * 32 + 16 + lr][(lane & 3) * 8];
  bf16* lb0 = &Bs[wave * 32 + lr][(lane & 3) * 8];
  bf16* lb1 = &Bs[wave * 32 + 16 + lr][(lane & 3) * 8];

  const int rc = ((quad ^ ((fl >> 1) & 3)) << 3);        // swizzled read chunk (elems)

  floatx4 acc[4][4];
#pragma unroll
  for (int mi = 0; mi < 4; ++mi)
#pragma unroll
    for (int ni = 0; ni < 4; ++ni) acc[mi][ni] = (floatx4){0.f, 0.f, 0.f, 0.f};

  for (int k0 = 0; k0 < kcnt; k0 += 32) {
    __syncthreads();
    gl_lds16(ga0 + k0, la0);
    gl_lds16(ga1 + k0, la1);
    gl_lds16(gb0 + k0, lb0);
    gl_lds16(gb1 + k0, lb1);
    __syncthreads();

    short8 af[4], bfv[4];
#pragma unroll
    for (int mi = 0; mi < 4; ++mi)
      af[mi] = *reinterpret_cast<const short8*>(&As[wm + mi * 16 + fl][rc]);
#pragma unroll
    for (int ni = 0; ni < 4; ++ni)
      bfv[ni] = *reinterpret_cast<const short8*>(&Bs[wn + ni * 16 + fl][rc]);
#pragma unroll
    for (int mi = 0; mi < 4; ++mi)
#pragma unroll
      for (int ni = 0; ni < 4; ++ni)
        acc[mi][ni] = __builtin_amdgcn_mfma_f32_16x16x32_bf16(af[mi], bfv[ni], acc[mi][ni], 0, 0, 0);
  }

#pragma unroll
  for (int mi = 0; mi < 4; ++mi) {
#pragma unroll
    for (int r = 0; r < 4; ++r) {
      const int row = m0b + wm + mi * 16 + quad * 4 + r;
#pragma unroll
      for (int ni = 0; ni < 4; ++ni) {
        const int col = n0b + wn + ni * 16 + fl;
        float v = acc[mi][ni][r];
        if (bias) v += bias[col];
        if (act_gelu) v = 0.5f * v * (1.0f + erff(v * 0.70710678118654752f));
        const size_t base = (size_t)row * N + col;
        if (resid) v += resid[base];
        if (of) of[base] = v;
        if (ob) ob[base] = __float2bfloat16(v);
      }
    }
  }
}

// ---------------------------------------------------------------------------
// 256x128 / BK=32 / 512-thread GEMM, counted-vmcnt 2-deep pipeline (T3+T4+T5).
// R5: 48 KiB dbuf LDS -> 3 blocks/CU (TLP hides stage/barrier windows);
//     grids 384/512/512; setprio around MFMA cluster.
// Staging: 3 block-wide gl_lds per K-tile (A:2, B:1), depth-2 -> vmcnt(3).
// Chunk-XOR swizzle both-sides (rule #21); XCD-bijective block swizzle.
// C[M,N] = A[M,Ktot] @ Bt[N,Ktot]^T; split-K via blockIdx.z -> outb + z*pstride.
// ---------------------------------------------------------------------------
__global__ __launch_bounds__(512, 6) void gemm256(
    const bf16* __restrict__ A, const bf16* __restrict__ Bt,
    int M, int N, int K, int Ktot, int lda, int ldb,
    const float* __restrict__ bias, int act_gelu,
    bf16* __restrict__ outb, int pstride)
{
  __shared__ __attribute__((aligned(16))) bf16 As[2][256 * 32];
  __shared__ __attribute__((aligned(16))) bf16 Bs[2][128 * 32];

  const int tid = threadIdx.x;
  const int wave = tid >> 6, lane = tid & 63;

  // XCD-bijective swizzle of the (x,y) linear block id (m204)
  const int gX = gridDim.x;
  const int nwg = gX * gridDim.y;
  int lin = blockIdx.y * gX + blockIdx.x;
  {
    const int q = nwg >> 3, r = nwg & 7;
    const int xcd = lin & 7, idx = lin >> 3;
    lin = (xcd < r ? xcd * (q + 1) : r * (q + 1) + (xcd - r) * q) + idx;
  }
  const int n0b = (lin % gX) << 7;   // 128-col tiles
  const int m0b = (lin / gX) << 8;   // 256-row tiles

  const int z = blockIdx.z;
  const int kbeg = z * K;
  const int nkt = min(K, Ktot - kbeg) >> 5;   // K-tiles of 32
  const bf16* Ab = A + (size_t)kbeg;
  const bf16* Bb = Bt + (size_t)kbeg;
  bf16* ob = outb + (size_t)z * pstride;

  // ---- staging: per K-tile 3 block-wide loads (A rows 0-127, A rows 128-255,
  // B rows 0-127). thread covers row tid>>2, chunk tid&3; global col chunk is
  // XOR-permuted so linear-LDS + swizzled reads see true k order.
  const int srow = tid >> 2;                        // 0..127
  const int scol = (((tid & 3) ^ (srow & 3)) << 3); // inverse-swizzled col (elems)
  const bf16* gA0 = Ab + (size_t)(m0b + srow) * lda + scol;
  const bf16* gA1 = gA0 + (size_t)128 * lda;
  const bf16* gB  = Bb + (size_t)(n0b + srow) * ldb + scol;
  bf16* lA[2] = {&As[0][tid * 8], &As[1][tid * 8]};
  bf16* lB[2] = {&Bs[0][tid * 8], &Bs[1][tid * 8]};

  // ---- fragment read addressing
  const int fl = lane & 15, quad = lane >> 4;
  const int wm = (wave >> 1) * 64;                  // 4 wave-rows x 64
  const int wn = (wave & 1) * 64;                   // 2 wave-cols x 64
  const int rch = ((quad ^ (fl & 3)) << 3);         // swizzled read chunk (elems)

  floatx4 acc[4][4];
#pragma unroll
  for (int mi = 0; mi < 4; ++mi)
#pragma unroll
    for (int ni = 0; ni < 4; ++ni) acc[mi][ni] = (floatx4){0.f, 0.f, 0.f, 0.f};

  // prologue: 2 K-tiles in flight (6 outstanding loads/thread)
  {
    gl_lds16(gA0, lA[0]);
    gl_lds16(gA1, lA[0] + 4096);
    gl_lds16(gB,  lB[0]);
  }
  if (nkt > 1) {
    gl_lds16(gA0 + 32, lA[1]);
    gl_lds16(gA1 + 32, lA[1] + 4096);
    gl_lds16(gB  + 32, lB[1]);
  }

  for (int kt = 0; kt < nkt; ++kt) {
    if (kt + 1 < nkt) {
      asm volatile("s_waitcnt vmcnt(3)" ::: "memory");   // tile kt landed; kt+1 in flight
    } else {
      asm volatile("s_waitcnt vmcnt(0)" ::: "memory");   // last tile: full drain
    }
    __builtin_amdgcn_s_barrier();
    __builtin_amdgcn_sched_barrier(0);

    const bf16* as = (kt & 1) ? &As[1][0] : &As[0][0];
    const bf16* bs = (kt & 1) ? &Bs[1][0] : &Bs[0][0];
    short8 af[4], bv[4];
#pragma unroll
    for (int mi = 0; mi < 4; ++mi)
      af[mi] = *reinterpret_cast<const short8*>(&as[(wm + mi * 16 + fl) * 32 + rch]);
#pragma unroll
    for (int ni = 0; ni < 4; ++ni)
      bv[ni] = *reinterpret_cast<const short8*>(&bs[(wn + ni * 16 + fl) * 32 + rch]);
    __builtin_amdgcn_s_setprio(1);
#pragma unroll
    for (int mi = 0; mi < 4; ++mi)
#pragma unroll
      for (int ni = 0; ni < 4; ++ni)
        acc[mi][ni] = __builtin_amdgcn_mfma_f32_16x16x32_bf16(af[mi], bv[ni], acc[mi][ni], 0, 0, 0);
    __builtin_amdgcn_s_setprio(0);
    __builtin_amdgcn_sched_barrier(0);
    __builtin_amdgcn_s_barrier();     // all waves done reading buf[kt&1]
    if (kt + 2 < nkt) {
      const int ko = (kt + 2) << 5;
      bf16* dA = (kt & 1) ? lA[1] : lA[0];
      bf16* dB = (kt & 1) ? lB[1] : lB[0];
      gl_lds16(gA0 + ko, dA);
      gl_lds16(gA1 + ko, dA + 4096);
      gl_lds16(gB  + ko, dB);
    }
  }

#pragma unroll
  for (int mi = 0; mi < 4; ++mi) {
#pragma unroll
    for (int r = 0; r < 4; ++r) {
      const int row = m0b + wm + mi * 16 + quad * 4 + r;
#pragma unroll
      for (int ni = 0; ni < 4; ++ni) {
        const int col = n0b + wn + ni * 16 + fl;
        float v = acc[mi][ni][r];
        if (bias) v += bias[col];
        if (act_gelu) v = 0.5f * v * (1.0f + erff(v * 0.70710678118654752f));
        ob[(size_t)row * N + col] = __float2bfloat16(v);
      }
    }
  }
}

// ---------------------------------------------------------------------------
// MFMA flash attention, fixed-base softmax (m == 0).
// Q fragments in registers; VT row-permutation sigma(d) = d ^ twoc kills the
// 4-way bank conflicts of the transpose scalar writes.
// ---------------------------------------------------------------------------
__global__ __launch_bounds__(256, 3) void attn_kernel(
    const bf16* __restrict__ qkv, const bf16* __restrict__ kr,
    const float* __restrict__ dsb, const float* __restrict__ seg_embed,
    const float* __restrict__ rwb, const float* __restrict__ rrb,
    const float* __restrict__ rsb,
    bf16* __restrict__ av_out)
{
  const int bx = blockIdx.x;
  const int n  = bx & 15;
  const int b  = (bx >> 4) & 3;
  const int it = 15 - (bx >> 6);     // heavy tiles first
  const int i0 = it * 64;
  const int tid = threadIdx.x;

  const bf16* qh = qkv + n * DH;
  const bf16* kh = qkv + ND + n * DH;
  const bf16* vh = qkv + 2 * ND + n * DH;

  __shared__ bf16 Kb[64][72];
  __shared__ bf16 VT[64][72];
  __shared__ bf16 krw[128][72];
  __shared__ bf16 bdrL[64][88];
  __shared__ float efs0[64], efs1[64];
  __shared__ float dsq[64], dsk[64];

  const int wave = tid >> 6, lane = tid & 63;
  const int fl = lane & 15, quad = lane >> 4;
  const int wq0 = wave * 16;
  const int tb0 = 3 - wave;
  const int twoc = (tid & 3) << 1;   // VT sigma: row XOR for this thread's d-block

  // ---- prologue: Q fragments in registers + ef sums ----
  short8 aw[2], ar[2];
  {
    const int qrow = i0 + wq0 + fl;
    const bf16* qp = qh + (size_t)(qrow * BB + b) * QKVS;
    float e0 = 0.f, e1 = 0.f;
#pragma unroll
    for (int ks = 0; ks < 2; ++ks) {
      const int d0 = ks * 32 + quad * 8;
      const uint4 qv = *reinterpret_cast<const uint4*>(qp + d0);
      const bf16* qe = reinterpret_cast<const bf16*>(&qv);
      bf16 wt[8], rt[8];
#pragma unroll
      for (int u = 0; u < 8; ++u) {
        const int d = d0 + u;
        const float qf = __bfloat162float(qe[u]);
        wt[u] = __float2bfloat16(qf + rwb[n * DH + d]);
        rt[u] = __float2bfloat16(qf + rrb[n * DH + d]);
        const float qs = qf + rsb[n * DH + d];
        e0 += qs * seg_embed[(0 * NH + n) * DH + d];
        e1 += qs * seg_embed[(1 * NH + n) * DH + d];
      }
      aw[ks] = *reinterpret_cast<short8*>(wt);
      ar[ks] = *reinterpret_cast<short8*>(rt);
    }
    // full-row sums live across the 4 quad-lanes of the same fl
    e0 += __shfl_xor(e0, 16, 64); e0 += __shfl_xor(e0, 32, 64);
    e1 += __shfl_xor(e1, 16, 64); e1 += __shfl_xor(e1, 32, 64);
    if (quad == 0) { efs0[wq0 + fl] = e0; efs1[wq0 + fl] = e1; }
    if (tid < 64) dsq[tid] = dsb[b * QLEN + i0 + tid];
  }

  floatx4 O[4];
#pragma unroll
  for (int nb = 0; nb < 4; ++nb) O[nb] = (floatx4){0.f, 0.f, 0.f, 0.f};
  float l_loc[4] = {0.f, 0.f, 0.f, 0.f};

  for (int jt = 0; jt <= it; ++jt) {
    const int j0 = jt * 64;
    const int kbase = QLEN + j0 - i0 - 63;

    __syncthreads();

    {
      const int j  = tid >> 2;
      const int dc = (tid & 3) << 4;
      const bf16* kp = kh + (size_t)((j0 + j) * BB + b) * QKVS + dc;
      const uint4 k0v = reinterpret_cast<const uint4*>(kp)[0];
      const uint4 k1v = reinterpret_cast<const uint4*>(kp)[1];
      reinterpret_cast<uint4*>(&Kb[j][dc])[0] = k0v;
      reinterpret_cast<uint4*>(&Kb[j][dc + 8])[0] = k1v;
      const bf16* vp = vh + (size_t)((j0 + j) * BB + b) * QKVS + dc;
      const uint4 v0v = reinterpret_cast<const uint4*>(vp)[0];
      const uint4 v1v = reinterpret_cast<const uint4*>(vp)[1];
      const bf16* ve0 = reinterpret_cast<const bf16*>(&v0v);
      const bf16* ve1 = reinterpret_cast<const bf16*>(&v1v);
#pragma unroll
      for (int u = 0; u < 8; ++u) {
        VT[dc + (u ^ twoc)][j] = ve0[u];
        VT[dc + 8 + (u ^ twoc)][j] = ve1[u];
      }
      const int t   = tid >> 1;
      const int dc2 = (tid & 1) << 5;
      const bf16* rp = kr + ((size_t)((kbase + t) * BB + b)) * ND + n * DH + dc2;
#pragma unroll
      for (int u = 0; u < 4; ++u)
        reinterpret_cast<uint4*>(&krw[t][dc2 + u * 8])[0] = reinterpret_cast<const uint4*>(rp)[u];
      if (tid < 64) dsk[tid] = dsb[b * QLEN + j0 + tid];
    }
    __syncthreads();

    floatx4 accS[4], accB[5];
#pragma unroll
    for (int nb = 0; nb < 4; ++nb) accS[nb] = (floatx4){0.f, 0.f, 0.f, 0.f};
#pragma unroll
    for (int u = 0; u < 5; ++u) accB[u] = (floatx4){0.f, 0.f, 0.f, 0.f};
#pragma unroll
    for (int ks = 0; ks < 2; ++ks) {
#pragma unroll
      for (int nb = 0; nb < 4; ++nb)
        accS[nb] = __builtin_amdgcn_mfma_f32_16x16x32_bf16(
            aw[ks], *reinterpret_cast<const short8*>(&Kb[nb * 16 + fl][ks * 32 + quad * 8]), accS[nb], 0, 0, 0);
#pragma unroll
      for (int u = 0; u < 5; ++u)
        accB[u] = __builtin_amdgcn_mfma_f32_16x16x32_bf16(
            ar[ks], *reinterpret_cast<const short8*>(&krw[(tb0 + u) * 16 + fl][ks * 32 + quad * 8]), accB[u], 0, 0, 0);
    }
#pragma unroll
    for (int u = 0; u < 5; ++u)
#pragma unroll
      for (int r = 0; r < 4; ++r)
        bdrL[wq0 + quad * 4 + r][u * 16 + fl] = __float2bfloat16(accB[u][r]);

    // ---- combine + mask + seg; fixed-base exp; P store ----
    float pv[4][4];
#pragma unroll
    for (int r = 0; r < 4; ++r) {
      const int qL = wq0 + quad * 4 + r;
      const int qg = i0 + qL;
      const float e0q = efs0[qL], e1q = efs1[qL];
      const float dq = dsq[qL];
#pragma unroll
      for (int nb = 0; nb < 4; ++nb) {
        const int kL = nb * 16 + fl;
        const int kg = j0 + kL;
        const float bdv = __bfloat162float(bdrL[qL][15 + kL - quad * 4 - r]);
        const float ef = (dq != dsk[kL]) ? e1q : e0q;
        const float s = (accS[nb][r] + bdv + ef) * SCALE;
        const float pe = (kg > qg) ? 0.0f : __expf(s);
        pv[nb][r] = pe;
        l_loc[r] += pe;
      }
    }

    // ---- P into own bdrL rows [0,64) (after all bdv reads; same wave) ----
#pragma unroll
    for (int nb = 0; nb < 4; ++nb)
#pragma unroll
      for (int r = 0; r < 4; ++r)
        bdrL[wq0 + quad * 4 + r][nb * 16 + fl] = __float2bfloat16(pv[nb][r]);

    // ---- PV MFMA: O[q][d] += P @ V  (VT rows sigma-permuted) ----
#pragma unroll
    for (int ks = 0; ks < 2; ++ks) {
      const short8 ap = *reinterpret_cast<const short8*>(&bdrL[wq0 + fl][ks * 32 + quad * 8]);
#pragma unroll
      for (int nb = 0; nb < 4; ++nb)
        O[nb] = __builtin_amdgcn_mfma_f32_16x16x32_bf16(
            ap, *reinterpret_cast<const short8*>(&VT[nb * 16 + (fl ^ (nb << 1))][ks * 32 + quad * 8]), O[nb], 0, 0, 0);
    }
  }

  // ---- epilogue: single l reduction (over fl lanes), normalize, store ----
  float inv[4];
#pragma unroll
  for (int r = 0; r < 4; ++r) {
    float l = l_loc[r];
    l += __shfl_xor(l, 1, 64);
    l += __shfl_xor(l, 2, 64);
    l += __shfl_xor(l, 4, 64);
    l += __shfl_xor(l, 8, 64);
    inv[r] = 1.0f / l;
  }
#pragma unroll
  for (int r = 0; r < 4; ++r) {
    const int qL = wq0 + quad * 4 + r;
    bf16* op = av_out + ((size_t)((i0 + qL) * BB + b)) * ND + n * DH;
#pragma unroll
    for (int nb = 0; nb < 4; ++nb)
      op[nb * 16 + fl] = __float2bfloat16(O[nb][r] * inv[r]);
  }
}

// ---------------------------------------------------------------------------
// LN1: x = pa + pb + resid; out = LN(x)*g + beta -> outf/outb.
// ---------------------------------------------------------------------------
__global__ __launch_bounds__(256) void ln_fused(
    const float* __restrict__ pa, const float* __restrict__ pb,
    const float* __restrict__ resid,
    const float* __restrict__ gg, const float* __restrict__ bbias,
    float* __restrict__ outf, bf16* __restrict__ outb)
{
  const int row = blockIdx.x;
  const int tid = threadIdx.x;
  __shared__ float red[4];
  const size_t base = (size_t)row * DMODEL;

  float v[4];
  float s = 0.0f;
#pragma unroll
  for (int k = 0; k < 4; ++k) {
    const int c = k * 256 + tid;
    const float x = pa[base + c] + pb[base + c] + resid[base + c];
    v[k] = x;
    s += x;
  }
#pragma unroll
  for (int off = 32; off; off >>= 1) s += __shfl_xor(s, off, 64);
  const int w = tid >> 6, lane = tid & 63;
  if (lane == 0) red[w] = s;
  __syncthreads();
  const float mean = (red[0] + red[1] + red[2] + red[3]) * (1.0f / DMODEL);

  float s2 = 0.0f;
#pragma unroll
  for (int k = 0; k < 4; ++k) {
    const float dlt = v[k] - mean;
    s2 += dlt * dlt;
  }
  __syncthreads();
#pragma unroll
  for (int off = 32; off; off >>= 1) s2 += __shfl_xor(s2, off, 64);
  if (lane == 0) red[w] = s2;
  __syncthreads();
  const float var = (red[0] + red[1] + red[2] + red[3]) * (1.0f / DMODEL);
  const float rstd = rsqrtf(var + 1e-12f);

#pragma unroll
  for (int k = 0; k < 4; ++k) {
    const int c = k * 256 + tid;
    const float o = (v[k] - mean) * rstd * gg[c] + bbias[c];
    if (outf) outf[base + c] = o;
    if (outb) outb[base + c] = __float2bfloat16(o);
  }
}

// ---------------------------------------------------------------------------
// LN2: x = pa+pb+pc+pd (bf16 partials) + resid + bias; out = LN(x)*g + beta.
// ---------------------------------------------------------------------------
__global__ __launch_bounds__(256) void ln_fused4b(
    const bf16* __restrict__ pa, const bf16* __restrict__ pb,
    const bf16* __restrict__ pc, const bf16* __restrict__ pd,
    const float* __restrict__ resid, const float* __restrict__ bias,
    const float* __restrict__ gg, const float* __restrict__ bbias,
    float* __restrict__ outf)
{
  const int row = blockIdx.x;
  const int tid = threadIdx.x;
  __shared__ float red[4];
  const size_t base = (size_t)row * DMODEL;

  float v[4];
  float s = 0.0f;
#pragma unroll
  for (int k = 0; k < 4; ++k) {
    const int c = k * 256 + tid;
    float x = __bfloat162float(pa[base + c]) + __bfloat162float(pb[base + c]) +
              __bfloat162float(pc[base + c]) + __bfloat162float(pd[base + c]) +
              resid[base + c] + bias[c];
    v[k] = x;
    s += x;
  }
#pragma unroll
  for (int off = 32; off; off >>= 1) s += __shfl_xor(s, off, 64);
  const int w = tid >> 6, lane = tid & 63;
  if (lane == 0) red[w] = s;
  __syncthreads();
  const float mean = (red[0] + red[1] + red[2] + red[3]) * (1.0f / DMODEL);

  float s2 = 0.0f;
#pragma unroll
  for (int k = 0; k < 4; ++k) {
    const float dlt = v[k] - mean;
    s2 += dlt * dlt;
  }
  __syncthreads();
#pragma unroll
  for (int off = 32; off; off >>= 1) s2 += __shfl_xor(s2, off, 64);
  if (lane == 0) red[w] = s2;
  __syncthreads();
  const float var = (red[0] + red[1] + red[2] + red[3]) * (1.0f / DMODEL);
  const float rstd = rsqrtf(var + 1e-12f);

#pragma unroll
  for (int k = 0; k < 4; ++k) {
    const int c = k * 256 + tid;
    outf[base + c] = (v[k] - mean) * rstd * gg[c] + bbias[c];
  }
}

// ---------------------------------------------------------------------------
extern "C" void kernel_launch(void* const* d_in, const int* in_sizes, int n_in,
                              void* d_out, int out_size, void* d_ws, size_t ws_size,
                              hipStream_t stream) {
  const float* h         = (const float*)d_in[0];
  const float* r         = (const float*)d_in[1];
  const float* seg_mat   = (const float*)d_in[3];
  const float* q_w       = (const float*)d_in[4];
  const float* k_w       = (const float*)d_in[5];
  const float* v_w       = (const float*)d_in[6];
  const float* o_w       = (const float*)d_in[7];
  const float* r_w       = (const float*)d_in[8];
  const float* r_r_bias  = (const float*)d_in[9];
  const float* r_s_bias  = (const float*)d_in[10];
  const float* r_w_bias  = (const float*)d_in[11];
  const float* seg_embed = (const float*)d_in[12];
  const float* ln1_g     = (const float*)d_in[13];
  const float* ln1_b     = (const float*)d_in[14];
  const float* ff_w1     = (const float*)d_in[15];
  const float* ff_b1     = (const float*)d_in[16];
  const float* ff_w2     = (const float*)d_in[17];
  const float* ff_b2     = (const float*)d_in[18];
  const float* ln2_g     = (const float*)d_in[19];
  const float* ln2_b     = (const float*)d_in[20];
  float* outp = (float*)d_out;

  const size_t M1 = (size_t)QLEN * BB;   // 4096
  const size_t MRU = (size_t)RUSED * BB; // 4608 (kr rows used)
  char* ws = (char*)d_ws;
  const size_t MB = 1u << 20;

  bf16* hb   = (bf16*)(ws + 0 * MB);     // 8 MB   [P0..P1]
  bf16* rb   = (bf16*)(ws + 8 * MB);     // 9 MB   [P0..P1]
  bf16* wqkvt= (bf16*)(ws + 24 * MB);    // 6 MB   [P0..P1]
  bf16* wrt  = (bf16*)(ws + 30 * MB);    // 2 MB   [P0..P1]
  bf16* wo   = (bf16*)(ws + 32 * MB);    // 2 MB   [P0..P3]
  bf16* w1t  = (bf16*)(ws + 34 * MB);    // 8 MB   [P0..P5]
  bf16* w2t  = (bf16*)(ws + 42 * MB);    // 8 MB   [P0..P6]
  bf16* qkvb = (bf16*)(ws + 50 * MB);    // 24 MB  [P1..P2]
  bf16* krb  = (bf16*)(ws + 74 * MB);    // 9 MB   [P1..P2]
  bf16* avb  = (bf16*)(ws + 90 * MB);    // 8 MB   [P2..P3]
  float* pa1  = (float*)(ws + 0 * MB);   // 16 MB [P3..P4] over hb/rb (dead)
  float* pb1  = (float*)(ws + 16 * MB);  // 16 MB [P3..P4] over rb tail+wqkvt+wrt (dead)
  float* out1 = (float*)(ws + 50 * MB);  // 16 MB [P4..P7] over qkvb (dead)
  bf16* out1b = (bf16*)(ws + 66 * MB);   // 8 MB  [P4..P5] over qkvb tail (dead)
  bf16* ff1   = (bf16*)(ws + 0 * MB);    // 32 MB [P5..P6] over pa1/pb1 (dead)
  bf16* p2    = (bf16*)(ws + 74 * MB);   // 4x8 MB [P6..P7] over krb+avb (dead): 74/82/90/98
  float* dsbuf = (float*)(ws + 106 * MB); // 16 KB [P0..P2]

  dim3 blk(256);
  dim3 blk512(512);

  // P0: fused conversions (r only first RUSED rows)
  cvt_all<<<dim3(4864), blk, 0, stream>>>(h, r, o_w, hb, rb, wo);
  tconv_all<<<dim3(12288), blk, 0, stream>>>(q_w, k_w, v_w, r_w, ff_w1, ff_w2,
                                             wqkvt, wrt, w1t, w2t);
  seg_extract<<<dim3(16), blk, 0, stream>>>(seg_mat, dsbuf);

  // P1: fused qkv projection (N=3072) via 256x128 counted-vmcnt; kr via 128^2
  gemm256<<<dim3(QKVS / 128, M1 / 256, 1), blk512, 0, stream>>>(
      hb, wqkvt, (int)M1, QKVS, DMODEL, DMODEL, DMODEL, DMODEL, nullptr, 0, qkvb, 0);
  gemm_bt<<<dim3(ND / 128, (int)(MRU / 128), 1), blk, 0, stream>>>(
      rb, wrt, (int)MRU, ND, DMODEL, DMODEL, DMODEL, DMODEL, nullptr, nullptr, 0, nullptr, krb, 0);

  // P2: fused relative attention (MFMA, fixed-base softmax)
  attn_kernel<<<dim3(16 * BB * NH), blk, 0, stream>>>(
      qkvb, krb, dsbuf, seg_embed,
      r_w_bias, r_r_bias, r_s_bias, avb);

  // P3: output projection, split-K=2 -> raw f32 partials pa1/pb1
  gemm_bt<<<dim3(DMODEL / 128, M1 / 128, 2), blk, 0, stream>>>(
      avb, wo, (int)M1, DMODEL, ND / 2, ND, ND, ND, nullptr, nullptr, 0, pa1, nullptr, (int)(M1 * DMODEL));

  // P4: LN1( pa1 + pb1 + h ) -> out1 f32 + out1b bf16
  ln_fused<<<dim3((int)M1), blk, 0, stream>>>(pa1, pb1, h, ln1_g, ln1_b, out1, out1b);

  // P5: FF1 gelu(out1@W1+b1) -> bf16, 256x128 counted-vmcnt
  gemm256<<<dim3(DI / 128, M1 / 256, 1), blk512, 0, stream>>>(
      out1b, w1t, (int)M1, DI, DMODEL, DMODEL, DMODEL, DMODEL, ff_b1, 1, ff1, 0);

  // P6: FF2 split-K=4 (K=1024 each) -> bf16 partials p2[0..3], 256x128 counted-vmcnt
  gemm256<<<dim3(DMODEL / 128, M1 / 256, 4), blk512, 0, stream>>>(
      ff1, w2t, (int)M1, DMODEL, DI / 4, DI, DI, DI, nullptr, 0, p2, (int)(M1 * DMODEL));

  // P7: LN2( p2[0..3] + b2 + out1 ) -> d_out
  ln_fused4b<<<dim3((int)M1), blk, 0, stream>>>(
      p2, p2 + M1 * DMODEL, p2 + 2 * M1 * DMODEL, p2 + 3 * M1 * DMODEL,
      out1, ff_b2, ln2_g, ln2_b, outp);
}

// Round 6
// 466.151 us; speedup vs baseline: 2.4778x; 2.4778x over previous
//
#include <hip/hip_runtime.h>
#include <hip/hip_bf16.h>

using bf16 = __hip_bfloat16;
typedef __attribute__((ext_vector_type(8))) short short8;
typedef __attribute__((ext_vector_type(4))) float floatx4;

#define QLEN 1024
#define KLEN 1024
#define RLEN 2048
#define RUSED 1152   /* kr rows actually referenced by attention: t in [1,1088] */
#define BB   4
#define DMODEL 1024
#define NH   16
#define DH   64
#define DI   4096
#define ND   1024
#define QKVS 3072   /* fused qkv row stride */
#define SCALE 0.125f

// async global->LDS, 16B per lane, wave-uniform LDS base + lane*16 layout
__device__ inline void gl_lds16(const bf16* g, bf16* l) {
  __builtin_amdgcn_global_load_lds(
      (__attribute__((address_space(1))) void*)(g),
      (__attribute__((address_space(3))) void*)(l), 16, 0, 0);
}

// ---------------------------------------------------------------------------
// Fused f32->bf16 converts for h | r(first RUSED rows) | o_w (flat decode).
// ---------------------------------------------------------------------------
__global__ __launch_bounds__(256) void cvt_all(
    const float* __restrict__ h, const float* __restrict__ r,
    const float* __restrict__ ow,
    bf16* __restrict__ hb, bf16* __restrict__ rb, bf16* __restrict__ wo)
{
  const int id = blockIdx.x;
  const float* src; bf16* dst; int off;
  if (id < 2048)      { src = h;  dst = hb; off = id * 2048; }
  else if (id < 4352) { src = r;  dst = rb; off = (id - 2048) * 2048; }
  else                { src = ow; dst = wo; off = (id - 4352) * 2048; }
  const int idx = off + threadIdx.x * 8;
  const float4 a = *reinterpret_cast<const float4*>(src + idx);
  const float4 b = *reinterpret_cast<const float4*>(src + idx + 4);
  bf16 o[8] = {__float2bfloat16(a.x), __float2bfloat16(a.y),
               __float2bfloat16(a.z), __float2bfloat16(a.w),
               __float2bfloat16(b.x), __float2bfloat16(b.y),
               __float2bfloat16(b.z), __float2bfloat16(b.w)};
  *reinterpret_cast<uint4*>(dst + idx) = *reinterpret_cast<uint4*>(o);
}

// ---------------------------------------------------------------------------
// Fused transpose+convert for q_w|k_w|v_w|r_w|ff_w1|ff_w2 (flat decode).
// ---------------------------------------------------------------------------
__device__ inline void tconv_tile(const float* __restrict__ src, bf16* __restrict__ dst,
                                  int R, int C, int bx, int by, int tid) {
  __shared__ float tile[32][33];
  const int r0 = by * 32, c0 = bx * 32;
  {
    const int tr = tid >> 3, tc = (tid & 7) * 4;
    const float4 f = *reinterpret_cast<const float4*>(src + (size_t)(r0 + tr) * C + c0 + tc);
    tile[tr][tc + 0] = f.x; tile[tr][tc + 1] = f.y;
    tile[tr][tc + 2] = f.z; tile[tr][tc + 3] = f.w;
  }
  __syncthreads();
  {
    const int oc = tid >> 3, orr = (tid & 7) * 4;
    bf16 o[4];
#pragma unroll
    for (int u = 0; u < 4; ++u) o[u] = __float2bfloat16(tile[orr + u][oc]);
    *reinterpret_cast<uint2*>(dst + (size_t)(c0 + oc) * R + r0 + orr) = *reinterpret_cast<uint2*>(o);
  }
}

__global__ __launch_bounds__(256) void tconv_all(
    const float* __restrict__ qw, const float* __restrict__ kw,
    const float* __restrict__ vw, const float* __restrict__ rw,
    const float* __restrict__ w1, const float* __restrict__ w2,
    bf16* __restrict__ wqkvt, bf16* __restrict__ wrt,
    bf16* __restrict__ w1t, bf16* __restrict__ w2t)
{
  const int id = blockIdx.x;
  const int tid = threadIdx.x;
  if (id < 4096) {
    const int part = id >> 10, local = id & 1023;
    const float* src = (part == 0) ? qw : (part == 1) ? kw : (part == 2) ? vw : rw;
    bf16* dst = (part < 3) ? (wqkvt + (size_t)part * ND * DMODEL) : wrt;
    tconv_tile(src, dst, DMODEL, ND, local & 31, local >> 5, tid);
  } else if (id < 8192) {
    const int local = id - 4096;
    tconv_tile(w1, w1t, DMODEL, DI, local & 127, local >> 7, tid);
  } else {
    const int local = id - 8192;
    tconv_tile(w2, w2t, DI, DMODEL, local & 31, local >> 5, tid);
  }
}

// ---------------------------------------------------------------------------
// seg_mat one-hot collapse: ds[b][i] = seg_mat[i, 0, b, 1]  (s_i XOR s_0).
// ---------------------------------------------------------------------------
__global__ __launch_bounds__(256) void seg_extract(const float* __restrict__ seg,
                                                   float* __restrict__ dsb) {
  const int idx = blockIdx.x * 256 + threadIdx.x;   // 4096
  const int i = idx >> 2, b = idx & 3;
  dsb[b * QLEN + i] = seg[(size_t)(i * KLEN * BB + b) * 2 + 1];
}

// ---------------------------------------------------------------------------
// MFMA bf16 GEMM: C[M,N] = A[M,Ktot] @ Bt[N,Ktot]^T, f32 accum.
// 128x128 tile, BK=32 (kept for kr / o-proj shapes).
// ---------------------------------------------------------------------------
__global__ __launch_bounds__(256) void gemm_bt(
    const bf16* __restrict__ A, const bf16* __restrict__ Bt,
    int M, int N, int K, int Ktot, int lda, int ldb,
    const float* __restrict__ bias, const float* __restrict__ resid, int act_gelu,
    float* __restrict__ outf, bf16* __restrict__ outb, int pstride)
{
  __shared__ bf16 As[128][32];
  __shared__ bf16 Bs[128][32];

  const int tid = threadIdx.x;
  const int m0b = blockIdx.y * 128;
  const int n0b = blockIdx.x * 128;
  const int z = blockIdx.z;
  const int kbeg = z * K;
  const int kcnt = min(K, Ktot - kbeg);
  A  += (size_t)kbeg;
  Bt += (size_t)kbeg;
  float* of = outf ? (outf + (size_t)z * pstride) : outf;
  bf16*  ob = outb ? (outb + (size_t)z * pstride) : outb;

  const int wave = tid >> 6, lane = tid & 63;
  const int wm = (wave & 1) * 64, wn = (wave >> 1) * 64;
  const int fl = lane & 15, quad = lane >> 4;

  const int lr = lane >> 2;                              // 0..15
  const int cg = (((lane & 3) ^ ((lr >> 1) & 3)) << 3);  // swizzled global chunk (elems)
  const bf16* ga0 = A  + (size_t)(m0b + wave * 32 + lr) * lda + cg;
  const bf16* ga1 = ga0 + (size_t)16 * lda;
  const bf16* gb0 = Bt + (size_t)(n0b + wave * 32 + lr) * ldb + cg;
  const bf16* gb1 = gb0 + (size_t)16 * ldb;
  bf16* la0 = &As[wave * 32 + lr][(lane & 3) * 8];
  bf16* la1 = &As[wave * 32 + 16 + lr][(lane & 3) * 8];
  bf16* lb0 = &Bs[wave * 32 + lr][(lane & 3) * 8];
  bf16* lb1 = &Bs[wave * 32 + 16 + lr][(lane & 3) * 8];

  const int rc = ((quad ^ ((fl >> 1) & 3)) << 3);        // swizzled read chunk (elems)

  floatx4 acc[4][4];
#pragma unroll
  for (int mi = 0; mi < 4; ++mi)
#pragma unroll
    for (int ni = 0; ni < 4; ++ni) acc[mi][ni] = (floatx4){0.f, 0.f, 0.f, 0.f};

  for (int k0 = 0; k0 < kcnt; k0 += 32) {
    __syncthreads();
    gl_lds16(ga0 + k0, la0);
    gl_lds16(ga1 + k0, la1);
    gl_lds16(gb0 + k0, lb0);
    gl_lds16(gb1 + k0, lb1);
    __syncthreads();

    short8 af[4], bfv[4];
#pragma unroll
    for (int mi = 0; mi < 4; ++mi)
      af[mi] = *reinterpret_cast<const short8*>(&As[wm + mi * 16 + fl][rc]);
#pragma unroll
    for (int ni = 0; ni < 4; ++ni)
      bfv[ni] = *reinterpret_cast<const short8*>(&Bs[wn + ni * 16 + fl][rc]);
#pragma unroll
    for (int mi = 0; mi < 4; ++mi)
#pragma unroll
      for (int ni = 0; ni < 4; ++ni)
        acc[mi][ni] = __builtin_amdgcn_mfma_f32_16x16x32_bf16(af[mi], bfv[ni], acc[mi][ni], 0, 0, 0);
  }

#pragma unroll
  for (int mi = 0; mi < 4; ++mi) {
#pragma unroll
    for (int r = 0; r < 4; ++r) {
      const int row = m0b + wm + mi * 16 + quad * 4 + r;
#pragma unroll
      for (int ni = 0; ni < 4; ++ni) {
        const int col = n0b + wn + ni * 16 + fl;
        float v = acc[mi][ni][r];
        if (bias) v += bias[col];
        if (act_gelu) v = 0.5f * v * (1.0f + erff(v * 0.70710678118654752f));
        const size_t base = (size_t)row * N + col;
        if (resid) v += resid[base];
        if (of) of[base] = v;
        if (ob) ob[base] = __float2bfloat16(v);
      }
    }
  }
}

// ---------------------------------------------------------------------------
// 128x128 / BK=64 / 512-thread GEMM, counted-vmcnt 2-deep pipeline (T3+T4+T5).
// R6: revert to R4's PROVEN conflict-free BK=64 addressing (0 conflicts
//     measured R2-R4); occupancy via smaller tile: 64 KiB LDS -> 2 blocks/CU;
//     __launch_bounds__(512,4) caps regs at 128 (kernel needs ~70; no spill).
// Staging: 4 block-wide gl_lds per K-tile (A:2, B:2), depth-2 -> vmcnt(4).
// Chunk-XOR swizzle both-sides (rule #21); XCD-bijective block swizzle.
// C[M,N] = A[M,Ktot] @ Bt[N,Ktot]^T; split-K via blockIdx.z -> outb + z*pstride.
// ---------------------------------------------------------------------------
__global__ __launch_bounds__(512, 4) void gemm256(
    const bf16* __restrict__ A, const bf16* __restrict__ Bt,
    int M, int N, int K, int Ktot, int lda, int ldb,
    const float* __restrict__ bias, int act_gelu,
    bf16* __restrict__ outb, int pstride)
{
  __shared__ __attribute__((aligned(16))) bf16 As[2][128 * 64];   // 16 KiB x2
  __shared__ __attribute__((aligned(16))) bf16 Bs[2][128 * 64];   // 16 KiB x2

  const int tid = threadIdx.x;
  const int wave = tid >> 6, lane = tid & 63;

  // XCD-bijective swizzle of the (x,y) linear block id (m204)
  const int gX = gridDim.x;
  const int nwg = gX * gridDim.y;
  int lin = blockIdx.y * gX + blockIdx.x;
  {
    const int q = nwg >> 3, r = nwg & 7;
    const int xcd = lin & 7, idx = lin >> 3;
    lin = (xcd < r ? xcd * (q + 1) : r * (q + 1) + (xcd - r) * q) + idx;
  }
  const int n0b = (lin % gX) << 7;   // 128-col tiles
  const int m0b = (lin / gX) << 7;   // 128-row tiles

  const int z = blockIdx.z;
  const int kbeg = z * K;
  const int nkt = min(K, Ktot - kbeg) >> 6;   // K-tiles of 64
  const bf16* Ab = A + (size_t)kbeg;
  const bf16* Bb = Bt + (size_t)kbeg;
  bf16* ob = outb + (size_t)z * pstride;

  // ---- staging (identical math to R4, 0 conflicts measured): lane covers
  // row (lane>>3), chunk (lane&7) of an 8-row stripe; LDS dest linear;
  // global col chunk XOR-permuted so swizzled reads see logical k order.
  const int srow = lane >> 3;                       // 0..7
  const int scol = ((lane & 7) ^ srow) << 3;        // inverse-swizzled global col (elems)
  const bf16* gA = Ab + (size_t)(m0b + wave * 8 + srow) * lda + scol;
  const bf16* gB = Bb + (size_t)(n0b + wave * 8 + srow) * ldb + scol;
  const int lofs = wave * (8 * 64) + lane * 8;
  bf16* lA[2] = {&As[0][lofs], &As[1][lofs]};
  bf16* lB[2] = {&Bs[0][lofs], &Bs[1][lofs]};

  // ---- fragment read addressing (row&7 == fl&7 for all frag rows)
  const int fl = lane & 15, quad = lane >> 4;
  const int wm = (wave >> 2) * 64;                  // 2 wave-rows x 64
  const int wn = (wave & 3) * 32;                   // 4 wave-cols x 32
  const int ch0 = (quad ^ (fl & 7)) << 3;           // ks=0 chunk (elems); ks=1: ^32

  floatx4 acc[4][2];
#pragma unroll
  for (int mi = 0; mi < 4; ++mi)
#pragma unroll
    for (int ni = 0; ni < 2; ++ni) acc[mi][ni] = (floatx4){0.f, 0.f, 0.f, 0.f};

  // prologue: 2 K-tiles in flight (8 outstanding block-wide loads)
  {
    gl_lds16(gA, lA[0]);
    gl_lds16(gA + (size_t)64 * lda, lA[0] + 4096);
    gl_lds16(gB, lB[0]);
    gl_lds16(gB + (size_t)64 * ldb, lB[0] + 4096);
  }
  if (nkt > 1) {
    gl_lds16(gA + 64, lA[1]);
    gl_lds16(gA + (size_t)64 * lda + 64, lA[1] + 4096);
    gl_lds16(gB + 64, lB[1]);
    gl_lds16(gB + (size_t)64 * ldb + 64, lB[1] + 4096);
  }

  for (int kt = 0; kt < nkt; ++kt) {
    if (kt + 1 < nkt) {
      asm volatile("s_waitcnt vmcnt(4)" ::: "memory");   // tile kt landed; kt+1 in flight
    } else {
      asm volatile("s_waitcnt vmcnt(0)" ::: "memory");   // last tile: full drain
    }
    __builtin_amdgcn_s_barrier();
    __builtin_amdgcn_sched_barrier(0);

    const bf16* as = (kt & 1) ? &As[1][0] : &As[0][0];
    const bf16* bs = (kt & 1) ? &Bs[1][0] : &Bs[0][0];
#pragma unroll
    for (int ks = 0; ks < 2; ++ks) {
      const int ch = ch0 ^ (ks << 5);
      short8 af[4], bv[2];
#pragma unroll
      for (int mi = 0; mi < 4; ++mi)
        af[mi] = *reinterpret_cast<const short8*>(&as[(wm + mi * 16 + fl) * 64 + ch]);
#pragma unroll
      for (int ni = 0; ni < 2; ++ni)
        bv[ni] = *reinterpret_cast<const short8*>(&bs[(wn + ni * 16 + fl) * 64 + ch]);
      __builtin_amdgcn_s_setprio(1);
#pragma unroll
      for (int mi = 0; mi < 4; ++mi)
#pragma unroll
        for (int ni = 0; ni < 2; ++ni)
          acc[mi][ni] = __builtin_amdgcn_mfma_f32_16x16x32_bf16(af[mi], bv[ni], acc[mi][ni], 0, 0, 0);
      __builtin_amdgcn_s_setprio(0);
    }
    __builtin_amdgcn_sched_barrier(0);
    __builtin_amdgcn_s_barrier();     // all waves done reading buf[kt&1]
    if (kt + 2 < nkt) {
      const size_t ko = (size_t)(kt + 2) << 6;
      bf16* dA = (kt & 1) ? lA[1] : lA[0];
      bf16* dB = (kt & 1) ? lB[1] : lB[0];
      gl_lds16(gA + ko, dA);
      gl_lds16(gA + (size_t)64 * lda + ko, dA + 4096);
      gl_lds16(gB + ko, dB);
      gl_lds16(gB + (size_t)64 * ldb + ko, dB + 4096);
    }
  }

#pragma unroll
  for (int mi = 0; mi < 4; ++mi) {
#pragma unroll
    for (int r = 0; r < 4; ++r) {
      const int row = m0b + wm + mi * 16 + quad * 4 + r;
#pragma unroll
      for (int ni = 0; ni < 2; ++ni) {
        const int col = n0b + wn + ni * 16 + fl;
        float v = acc[mi][ni][r];
        if (bias) v += bias[col];
        if (act_gelu) v = 0.5f * v * (1.0f + erff(v * 0.70710678118654752f));
        ob[(size_t)row * N + col] = __float2bfloat16(v);
      }
    }
  }
}

// ---------------------------------------------------------------------------
// MFMA flash attention, fixed-base softmax (m == 0).
// Q fragments in registers; VT row-permutation sigma(d) = d ^ twoc kills the
// 4-way bank conflicts of the transpose scalar writes.
// ---------------------------------------------------------------------------
__global__ __launch_bounds__(256, 3) void attn_kernel(
    const bf16* __restrict__ qkv, const bf16* __restrict__ kr,
    const float* __restrict__ dsb, const float* __restrict__ seg_embed,
    const float* __restrict__ rwb, const float* __restrict__ rrb,
    const float* __restrict__ rsb,
    bf16* __restrict__ av_out)
{
  const int bx = blockIdx.x;
  const int n  = bx & 15;
  const int b  = (bx >> 4) & 3;
  const int it = 15 - (bx >> 6);     // heavy tiles first
  const int i0 = it * 64;
  const int tid = threadIdx.x;

  const bf16* qh = qkv + n * DH;
  const bf16* kh = qkv + ND + n * DH;
  const bf16* vh = qkv + 2 * ND + n * DH;

  __shared__ bf16 Kb[64][72];
  __shared__ bf16 VT[64][72];
  __shared__ bf16 krw[128][72];
  __shared__ bf16 bdrL[64][88];
  __shared__ float efs0[64], efs1[64];
  __shared__ float dsq[64], dsk[64];

  const int wave = tid >> 6, lane = tid & 63;
  const int fl = lane & 15, quad = lane >> 4;
  const int wq0 = wave * 16;
  const int tb0 = 3 - wave;
  const int twoc = (tid & 3) << 1;   // VT sigma: row XOR for this thread's d-block

  // ---- prologue: Q fragments in registers + ef sums ----
  short8 aw[2], ar[2];
  {
    const int qrow = i0 + wq0 + fl;
    const bf16* qp = qh + (size_t)(qrow * BB + b) * QKVS;
    float e0 = 0.f, e1 = 0.f;
#pragma unroll
    for (int ks = 0; ks < 2; ++ks) {
      const int d0 = ks * 32 + quad * 8;
      const uint4 qv = *reinterpret_cast<const uint4*>(qp + d0);
      const bf16* qe = reinterpret_cast<const bf16*>(&qv);
      bf16 wt[8], rt[8];
#pragma unroll
      for (int u = 0; u < 8; ++u) {
        const int d = d0 + u;
        const float qf = __bfloat162float(qe[u]);
        wt[u] = __float2bfloat16(qf + rwb[n * DH + d]);
        rt[u] = __float2bfloat16(qf + rrb[n * DH + d]);
        const float qs = qf + rsb[n * DH + d];
        e0 += qs * seg_embed[(0 * NH + n) * DH + d];
        e1 += qs * seg_embed[(1 * NH + n) * DH + d];
      }
      aw[ks] = *reinterpret_cast<short8*>(wt);
      ar[ks] = *reinterpret_cast<short8*>(rt);
    }
    // full-row sums live across the 4 quad-lanes of the same fl
    e0 += __shfl_xor(e0, 16, 64); e0 += __shfl_xor(e0, 32, 64);
    e1 += __shfl_xor(e1, 16, 64); e1 += __shfl_xor(e1, 32, 64);
    if (quad == 0) { efs0[wq0 + fl] = e0; efs1[wq0 + fl] = e1; }
    if (tid < 64) dsq[tid] = dsb[b * QLEN + i0 + tid];
  }

  floatx4 O[4];
#pragma unroll
  for (int nb = 0; nb < 4; ++nb) O[nb] = (floatx4){0.f, 0.f, 0.f, 0.f};
  float l_loc[4] = {0.f, 0.f, 0.f, 0.f};

  for (int jt = 0; jt <= it; ++jt) {
    const int j0 = jt * 64;
    const int kbase = QLEN + j0 - i0 - 63;

    __syncthreads();

    {
      const int j  = tid >> 2;
      const int dc = (tid & 3) << 4;
      const bf16* kp = kh + (size_t)((j0 + j) * BB + b) * QKVS + dc;
      const uint4 k0v = reinterpret_cast<const uint4*>(kp)[0];
      const uint4 k1v = reinterpret_cast<const uint4*>(kp)[1];
      reinterpret_cast<uint4*>(&Kb[j][dc])[0] = k0v;
      reinterpret_cast<uint4*>(&Kb[j][dc + 8])[0] = k1v;
      const bf16* vp = vh + (size_t)((j0 + j) * BB + b) * QKVS + dc;
      const uint4 v0v = reinterpret_cast<const uint4*>(vp)[0];
      const uint4 v1v = reinterpret_cast<const uint4*>(vp)[1];
      const bf16* ve0 = reinterpret_cast<const bf16*>(&v0v);
      const bf16* ve1 = reinterpret_cast<const bf16*>(&v1v);
#pragma unroll
      for (int u = 0; u < 8; ++u) {
        VT[dc + (u ^ twoc)][j] = ve0[u];
        VT[dc + 8 + (u ^ twoc)][j] = ve1[u];
      }
      const int t   = tid >> 1;
      const int dc2 = (tid & 1) << 5;
      const bf16* rp = kr + ((size_t)((kbase + t) * BB + b)) * ND + n * DH + dc2;
#pragma unroll
      for (int u = 0; u < 4; ++u)
        reinterpret_cast<uint4*>(&krw[t][dc2 + u * 8])[0] = reinterpret_cast<const uint4*>(rp)[u];
      if (tid < 64) dsk[tid] = dsb[b * QLEN + j0 + tid];
    }
    __syncthreads();

    floatx4 accS[4], accB[5];
#pragma unroll
    for (int nb = 0; nb < 4; ++nb) accS[nb] = (floatx4){0.f, 0.f, 0.f, 0.f};
#pragma unroll
    for (int u = 0; u < 5; ++u) accB[u] = (floatx4){0.f, 0.f, 0.f, 0.f};
#pragma unroll
    for (int ks = 0; ks < 2; ++ks) {
#pragma unroll
      for (int nb = 0; nb < 4; ++nb)
        accS[nb] = __builtin_amdgcn_mfma_f32_16x16x32_bf16(
            aw[ks], *reinterpret_cast<const short8*>(&Kb[nb * 16 + fl][ks * 32 + quad * 8]), accS[nb], 0, 0, 0);
#pragma unroll
      for (int u = 0; u < 5; ++u)
        accB[u] = __builtin_amdgcn_mfma_f32_16x16x32_bf16(
            ar[ks], *reinterpret_cast<const short8*>(&krw[(tb0 + u) * 16 + fl][ks * 32 + quad * 8]), accB[u], 0, 0, 0);
    }
#pragma unroll
    for (int u = 0; u < 5; ++u)
#pragma unroll
      for (int r = 0; r < 4; ++r)
        bdrL[wq0 + quad * 4 + r][u * 16 + fl] = __float2bfloat16(accB[u][r]);

    // ---- combine + mask + seg; fixed-base exp; P store ----
    float pv[4][4];
#pragma unroll
    for (int r = 0; r < 4; ++r) {
      const int qL = wq0 + quad * 4 + r;
      const int qg = i0 + qL;
      const float e0q = efs0[qL], e1q = efs1[qL];
      const float dq = dsq[qL];
#pragma unroll
      for (int nb = 0; nb < 4; ++nb) {
        const int kL = nb * 16 + fl;
        const int kg = j0 + kL;
        const float bdv = __bfloat162float(bdrL[qL][15 + kL - quad * 4 - r]);
        const float ef = (dq != dsk[kL]) ? e1q : e0q;
        const float s = (accS[nb][r] + bdv + ef) * SCALE;
        const float pe = (kg > qg) ? 0.0f : __expf(s);
        pv[nb][r] = pe;
        l_loc[r] += pe;
      }
    }

    // ---- P into own bdrL rows [0,64) (after all bdv reads; same wave) ----
#pragma unroll
    for (int nb = 0; nb < 4; ++nb)
#pragma unroll
      for (int r = 0; r < 4; ++r)
        bdrL[wq0 + quad * 4 + r][nb * 16 + fl] = __float2bfloat16(pv[nb][r]);

    // ---- PV MFMA: O[q][d] += P @ V  (VT rows sigma-permuted) ----
#pragma unroll
    for (int ks = 0; ks < 2; ++ks) {
      const short8 ap = *reinterpret_cast<const short8*>(&bdrL[wq0 + fl][ks * 32 + quad * 8]);
#pragma unroll
      for (int nb = 0; nb < 4; ++nb)
        O[nb] = __builtin_amdgcn_mfma_f32_16x16x32_bf16(
            ap, *reinterpret_cast<const short8*>(&VT[nb * 16 + (fl ^ (nb << 1))][ks * 32 + quad * 8]), O[nb], 0, 0, 0);
    }
  }

  // ---- epilogue: single l reduction (over fl lanes), normalize, store ----
  float inv[4];
#pragma unroll
  for (int r = 0; r < 4; ++r) {
    float l = l_loc[r];
    l += __shfl_xor(l, 1, 64);
    l += __shfl_xor(l, 2, 64);
    l += __shfl_xor(l, 4, 64);
    l += __shfl_xor(l, 8, 64);
    inv[r] = 1.0f / l;
  }
#pragma unroll
  for (int r = 0; r < 4; ++r) {
    const int qL = wq0 + quad * 4 + r;
    bf16* op = av_out + ((size_t)((i0 + qL) * BB + b)) * ND + n * DH;
#pragma unroll
    for (int nb = 0; nb < 4; ++nb)
      op[nb * 16 + fl] = __float2bfloat16(O[nb][r] * inv[r]);
  }
}

// ---------------------------------------------------------------------------
// LN1: x = pa + pb + resid; out = LN(x)*g + beta -> outf/outb.
// ---------------------------------------------------------------------------
__global__ __launch_bounds__(256) void ln_fused(
    const float* __restrict__ pa, const float* __restrict__ pb,
    const float* __restrict__ resid,
    const float* __restrict__ gg, const float* __restrict__ bbias,
    float* __restrict__ outf, bf16* __restrict__ outb)
{
  const int row = blockIdx.x;
  const int tid = threadIdx.x;
  __shared__ float red[4];
  const size_t base = (size_t)row * DMODEL;

  float v[4];
  float s = 0.0f;
#pragma unroll
  for (int k = 0; k < 4; ++k) {
    const int c = k * 256 + tid;
    const float x = pa[base + c] + pb[base + c] + resid[base + c];
    v[k] = x;
    s += x;
  }
#pragma unroll
  for (int off = 32; off; off >>= 1) s += __shfl_xor(s, off, 64);
  const int w = tid >> 6, lane = tid & 63;
  if (lane == 0) red[w] = s;
  __syncthreads();
  const float mean = (red[0] + red[1] + red[2] + red[3]) * (1.0f / DMODEL);

  float s2 = 0.0f;
#pragma unroll
  for (int k = 0; k < 4; ++k) {
    const float dlt = v[k] - mean;
    s2 += dlt * dlt;
  }
  __syncthreads();
#pragma unroll
  for (int off = 32; off; off >>= 1) s2 += __shfl_xor(s2, off, 64);
  if (lane == 0) red[w] = s2;
  __syncthreads();
  const float var = (red[0] + red[1] + red[2] + red[3]) * (1.0f / DMODEL);
  const float rstd = rsqrtf(var + 1e-12f);

#pragma unroll
  for (int k = 0; k < 4; ++k) {
    const int c = k * 256 + tid;
    const float o = (v[k] - mean) * rstd * gg[c] + bbias[c];
    if (outf) outf[base + c] = o;
    if (outb) outb[base + c] = __float2bfloat16(o);
  }
}

// ---------------------------------------------------------------------------
// LN2: x = pa+pb+pc+pd (bf16 partials) + resid + bias; out = LN(x)*g + beta.
// ---------------------------------------------------------------------------
__global__ __launch_bounds__(256) void ln_fused4b(
    const bf16* __restrict__ pa, const bf16* __restrict__ pb,
    const bf16* __restrict__ pc, const bf16* __restrict__ pd,
    const float* __restrict__ resid, const float* __restrict__ bias,
    const float* __restrict__ gg, const float* __restrict__ bbias,
    float* __restrict__ outf)
{
  const int row = blockIdx.x;
  const int tid = threadIdx.x;
  __shared__ float red[4];
  const size_t base = (size_t)row * DMODEL;

  float v[4];
  float s = 0.0f;
#pragma unroll
  for (int k = 0; k < 4; ++k) {
    const int c = k * 256 + tid;
    float x = __bfloat162float(pa[base + c]) + __bfloat162float(pb[base + c]) +
              __bfloat162float(pc[base + c]) + __bfloat162float(pd[base + c]) +
              resid[base + c] + bias[c];
    v[k] = x;
    s += x;
  }
#pragma unroll
  for (int off = 32; off; off >>= 1) s += __shfl_xor(s, off, 64);
  const int w = tid >> 6, lane = tid & 63;
  if (lane == 0) red[w] = s;
  __syncthreads();
  const float mean = (red[0] + red[1] + red[2] + red[3]) * (1.0f / DMODEL);

  float s2 = 0.0f;
#pragma unroll
  for (int k = 0; k < 4; ++k) {
    const float dlt = v[k] - mean;
    s2 += dlt * dlt;
  }
  __syncthreads();
#pragma unroll
  for (int off = 32; off; off >>= 1) s2 += __shfl_xor(s2, off, 64);
  if (lane == 0) red[w] = s2;
  __syncthreads();
  const float var = (red[0] + red[1] + red[2] + red[3]) * (1.0f / DMODEL);
  const float rstd = rsqrtf(var + 1e-12f);

#pragma unroll
  for (int k = 0; k < 4; ++k) {
    const int c = k * 256 + tid;
    outf[base + c] = (v[k] - mean) * rstd * gg[c] + bbias[c];
  }
}

// ---------------------------------------------------------------------------
extern "C" void kernel_launch(void* const* d_in, const int* in_sizes, int n_in,
                              void* d_out, int out_size, void* d_ws, size_t ws_size,
                              hipStream_t stream) {
  const float* h         = (const float*)d_in[0];
  const float* r         = (const float*)d_in[1];
  const float* seg_mat   = (const float*)d_in[3];
  const float* q_w       = (const float*)d_in[4];
  const float* k_w       = (const float*)d_in[5];
  const float* v_w       = (const float*)d_in[6];
  const float* o_w       = (const float*)d_in[7];
  const float* r_w       = (const float*)d_in[8];
  const float* r_r_bias  = (const float*)d_in[9];
  const float* r_s_bias  = (const float*)d_in[10];
  const float* r_w_bias  = (const float*)d_in[11];
  const float* seg_embed = (const float*)d_in[12];
  const float* ln1_g     = (const float*)d_in[13];
  const float* ln1_b     = (const float*)d_in[14];
  const float* ff_w1     = (const float*)d_in[15];
  const float* ff_b1     = (const float*)d_in[16];
  const float* ff_w2     = (const float*)d_in[17];
  const float* ff_b2     = (const float*)d_in[18];
  const float* ln2_g     = (const float*)d_in[19];
  const float* ln2_b     = (const float*)d_in[20];
  float* outp = (float*)d_out;

  const size_t M1 = (size_t)QLEN * BB;   // 4096
  const size_t MRU = (size_t)RUSED * BB; // 4608 (kr rows used)
  char* ws = (char*)d_ws;
  const size_t MB = 1u << 20;

  bf16* hb   = (bf16*)(ws + 0 * MB);     // 8 MB   [P0..P1]
  bf16* rb   = (bf16*)(ws + 8 * MB);     // 9 MB   [P0..P1]
  bf16* wqkvt= (bf16*)(ws + 24 * MB);    // 6 MB   [P0..P1]
  bf16* wrt  = (bf16*)(ws + 30 * MB);    // 2 MB   [P0..P1]
  bf16* wo   = (bf16*)(ws + 32 * MB);    // 2 MB   [P0..P3]
  bf16* w1t  = (bf16*)(ws + 34 * MB);    // 8 MB   [P0..P5]
  bf16* w2t  = (bf16*)(ws + 42 * MB);    // 8 MB   [P0..P6]
  bf16* qkvb = (bf16*)(ws + 50 * MB);    // 24 MB  [P1..P2]
  bf16* krb  = (bf16*)(ws + 74 * MB);    // 9 MB   [P1..P2]
  bf16* avb  = (bf16*)(ws + 90 * MB);    // 8 MB   [P2..P3]
  float* pa1  = (float*)(ws + 0 * MB);   // 16 MB [P3..P4] over hb/rb (dead)
  float* pb1  = (float*)(ws + 16 * MB);  // 16 MB [P3..P4] over rb tail+wqkvt+wrt (dead)
  float* out1 = (float*)(ws + 50 * MB);  // 16 MB [P4..P7] over qkvb (dead)
  bf16* out1b = (bf16*)(ws + 66 * MB);   // 8 MB  [P4..P5] over qkvb tail (dead)
  bf16* ff1   = (bf16*)(ws + 0 * MB);    // 32 MB [P5..P6] over pa1/pb1 (dead)
  bf16* p2    = (bf16*)(ws + 74 * MB);   // 4x8 MB [P6..P7] over krb+avb (dead): 74/82/90/98
  float* dsbuf = (float*)(ws + 106 * MB); // 16 KB [P0..P2]

  dim3 blk(256);
  dim3 blk512(512);

  // P0: fused conversions (r only first RUSED rows)
  cvt_all<<<dim3(4864), blk, 0, stream>>>(h, r, o_w, hb, rb, wo);
  tconv_all<<<dim3(12288), blk, 0, stream>>>(q_w, k_w, v_w, r_w, ff_w1, ff_w2,
                                             wqkvt, wrt, w1t, w2t);
  seg_extract<<<dim3(16), blk, 0, stream>>>(seg_mat, dsbuf);

  // P1: fused qkv projection (N=3072) via 128^2 counted-vmcnt; kr via 128^2/BK32
  gemm256<<<dim3(QKVS / 128, M1 / 128, 1), blk512, 0, stream>>>(
      hb, wqkvt, (int)M1, QKVS, DMODEL, DMODEL, DMODEL, DMODEL, nullptr, 0, qkvb, 0);
  gemm_bt<<<dim3(ND / 128, (int)(MRU / 128), 1), blk, 0, stream>>>(
      rb, wrt, (int)MRU, ND, DMODEL, DMODEL, DMODEL, DMODEL, nullptr, nullptr, 0, nullptr, krb, 0);

  // P2: fused relative attention (MFMA, fixed-base softmax)
  attn_kernel<<<dim3(16 * BB * NH), blk, 0, stream>>>(
      qkvb, krb, dsbuf, seg_embed,
      r_w_bias, r_r_bias, r_s_bias, avb);

  // P3: output projection, split-K=2 -> raw f32 partials pa1/pb1
  gemm_bt<<<dim3(DMODEL / 128, M1 / 128, 2), blk, 0, stream>>>(
      avb, wo, (int)M1, DMODEL, ND / 2, ND, ND, ND, nullptr, nullptr, 0, pa1, nullptr, (int)(M1 * DMODEL));

  // P4: LN1( pa1 + pb1 + h ) -> out1 f32 + out1b bf16
  ln_fused<<<dim3((int)M1), blk, 0, stream>>>(pa1, pb1, h, ln1_g, ln1_b, out1, out1b);

  // P5: FF1 gelu(out1@W1+b1) -> bf16, 128^2 counted-vmcnt
  gemm256<<<dim3(DI / 128, M1 / 128, 1), blk512, 0, stream>>>(
      out1b, w1t, (int)M1, DI, DMODEL, DMODEL, DMODEL, DMODEL, ff_b1, 1, ff1, 0);

  // P6: FF2 split-K=4 (K=1024 each) -> bf16 partials p2[0..3], 128^2 counted-vmcnt
  gemm256<<<dim3(DMODEL / 128, M1 / 128, 4), blk512, 0, stream>>>(
      ff1, w2t, (int)M1, DMODEL, DI / 4, DI, DI, DI, nullptr, 0, p2, (int)(M1 * DMODEL));

  // P7: LN2( p2[0..3] + b2 + out1 ) -> d_out
  ln_fused4b<<<dim3((int)M1), blk, 0, stream>>>(
      p2, p2 + M1 * DMODEL, p2 + 2 * M1 * DMODEL, p2 + 3 * M1 * DMODEL,
      out1, ff_b2, ln2_g, ln2_b, outp);
}

// Round 7
// 432.049 us; speedup vs baseline: 2.6733x; 1.0789x over previous
//
#include <hip/hip_runtime.h>
#include <hip/hip_bf16.h>

using bf16 = __hip_bfloat16;
typedef __attribute__((ext_vector_type(8))) short short8;
typedef __attribute__((ext_vector_type(4))) float floatx4;

#define QLEN 1024
#define KLEN 1024
#define RLEN 2048
#define RUSED 1152   /* kr rows actually referenced by attention: t in [1,1088] */
#define BB   4
#define DMODEL 1024
#define NH   16
#define DH   64
#define DI   4096
#define ND   1024
#define QKVS 3072   /* fused qkv row stride */
#define SCALE 0.125f

// async global->LDS, 16B per lane, wave-uniform LDS base + lane*16 layout
__device__ inline void gl_lds16(const bf16* g, bf16* l) {
  __builtin_amdgcn_global_load_lds(
      (__attribute__((address_space(1))) void*)(g),
      (__attribute__((address_space(3))) void*)(l), 16, 0, 0);
}

// ---------------------------------------------------------------------------
// Fused f32->bf16 converts for h | r(first RUSED rows) | o_w (flat decode).
// ---------------------------------------------------------------------------
__global__ __launch_bounds__(256) void cvt_all(
    const float* __restrict__ h, const float* __restrict__ r,
    const float* __restrict__ ow,
    bf16* __restrict__ hb, bf16* __restrict__ rb, bf16* __restrict__ wo)
{
  const int id = blockIdx.x;
  const float* src; bf16* dst; int off;
  if (id < 2048)      { src = h;  dst = hb; off = id * 2048; }
  else if (id < 4352) { src = r;  dst = rb; off = (id - 2048) * 2048; }
  else                { src = ow; dst = wo; off = (id - 4352) * 2048; }
  const int idx = off + threadIdx.x * 8;
  const float4 a = *reinterpret_cast<const float4*>(src + idx);
  const float4 b = *reinterpret_cast<const float4*>(src + idx + 4);
  bf16 o[8] = {__float2bfloat16(a.x), __float2bfloat16(a.y),
               __float2bfloat16(a.z), __float2bfloat16(a.w),
               __float2bfloat16(b.x), __float2bfloat16(b.y),
               __float2bfloat16(b.z), __float2bfloat16(b.w)};
  *reinterpret_cast<uint4*>(dst + idx) = *reinterpret_cast<uint4*>(o);
}

// ---------------------------------------------------------------------------
// Fused transpose+convert for q_w|k_w|v_w|r_w|ff_w1|ff_w2 (flat decode).
// ---------------------------------------------------------------------------
__device__ inline void tconv_tile(const float* __restrict__ src, bf16* __restrict__ dst,
                                  int R, int C, int bx, int by, int tid) {
  __shared__ float tile[32][33];
  const int r0 = by * 32, c0 = bx * 32;
  {
    const int tr = tid >> 3, tc = (tid & 7) * 4;
    const float4 f = *reinterpret_cast<const float4*>(src + (size_t)(r0 + tr) * C + c0 + tc);
    tile[tr][tc + 0] = f.x; tile[tr][tc + 1] = f.y;
    tile[tr][tc + 2] = f.z; tile[tr][tc + 3] = f.w;
  }
  __syncthreads();
  {
    const int oc = tid >> 3, orr = (tid & 7) * 4;
    bf16 o[4];
#pragma unroll
    for (int u = 0; u < 4; ++u) o[u] = __float2bfloat16(tile[orr + u][oc]);
    *reinterpret_cast<uint2*>(dst + (size_t)(c0 + oc) * R + r0 + orr) = *reinterpret_cast<uint2*>(o);
  }
}

__global__ __launch_bounds__(256) void tconv_all(
    const float* __restrict__ qw, const float* __restrict__ kw,
    const float* __restrict__ vw, const float* __restrict__ rw,
    const float* __restrict__ w1, const float* __restrict__ w2,
    bf16* __restrict__ wqkvt, bf16* __restrict__ wrt,
    bf16* __restrict__ w1t, bf16* __restrict__ w2t)
{
  const int id = blockIdx.x;
  const int tid = threadIdx.x;
  if (id < 4096) {
    const int part = id >> 10, local = id & 1023;
    const float* src = (part == 0) ? qw : (part == 1) ? kw : (part == 2) ? vw : rw;
    bf16* dst = (part < 3) ? (wqkvt + (size_t)part * ND * DMODEL) : wrt;
    tconv_tile(src, dst, DMODEL, ND, local & 31, local >> 5, tid);
  } else if (id < 8192) {
    const int local = id - 4096;
    tconv_tile(w1, w1t, DMODEL, DI, local & 127, local >> 7, tid);
  } else {
    const int local = id - 8192;
    tconv_tile(w2, w2t, DI, DMODEL, local & 31, local >> 5, tid);
  }
}

// ---------------------------------------------------------------------------
// seg_mat one-hot collapse: ds[b][i] = seg_mat[i, 0, b, 1]  (s_i XOR s_0).
// ---------------------------------------------------------------------------
__global__ __launch_bounds__(256) void seg_extract(const float* __restrict__ seg,
                                                   float* __restrict__ dsb) {
  const int idx = blockIdx.x * 256 + threadIdx.x;   // 4096
  const int i = idx >> 2, b = idx & 3;
  dsb[b * QLEN + i] = seg[(size_t)(i * KLEN * BB + b) * 2 + 1];
}

// ---------------------------------------------------------------------------
// 128x128 / BK=64 / 512-thread GEMM, counted-vmcnt 2-deep pipeline (T3+T4+T5).
// R7: + optional f32 output (outf; used by o-proj partials). Addressing is
// the R4/R6-proven conflict-free BK=64 scheme (0 conflicts measured R2-R6).
// Staging: 4 block-wide gl_lds per K-tile (A:2, B:2), depth-2 -> vmcnt(4).
// Chunk-XOR swizzle both-sides (rule #21); XCD-bijective block swizzle.
// C[M,N] = A[M,Ktot] @ Bt[N,Ktot]^T; split-K via blockIdx.z -> out + z*pstride.
// ---------------------------------------------------------------------------
__global__ __launch_bounds__(512, 4) void gemm256(
    const bf16* __restrict__ A, const bf16* __restrict__ Bt,
    int M, int N, int K, int Ktot, int lda, int ldb,
    const float* __restrict__ bias, int act_gelu,
    float* __restrict__ outf, bf16* __restrict__ outb, int pstride)
{
  __shared__ __attribute__((aligned(16))) bf16 As[2][128 * 64];   // 16 KiB x2
  __shared__ __attribute__((aligned(16))) bf16 Bs[2][128 * 64];   // 16 KiB x2

  const int tid = threadIdx.x;
  const int wave = tid >> 6, lane = tid & 63;

  // XCD-bijective swizzle of the (x,y) linear block id (m204)
  const int gX = gridDim.x;
  const int nwg = gX * gridDim.y;
  int lin = blockIdx.y * gX + blockIdx.x;
  {
    const int q = nwg >> 3, r = nwg & 7;
    const int xcd = lin & 7, idx = lin >> 3;
    lin = (xcd < r ? xcd * (q + 1) : r * (q + 1) + (xcd - r) * q) + idx;
  }
  const int n0b = (lin % gX) << 7;   // 128-col tiles
  const int m0b = (lin / gX) << 7;   // 128-row tiles

  const int z = blockIdx.z;
  const int kbeg = z * K;
  const int nkt = min(K, Ktot - kbeg) >> 6;   // K-tiles of 64
  const bf16* Ab = A + (size_t)kbeg;
  const bf16* Bb = Bt + (size_t)kbeg;
  float* of = outf ? (outf + (size_t)z * pstride) : outf;
  bf16*  ob = outb ? (outb + (size_t)z * pstride) : outb;

  // ---- staging (identical math to R4/R6, 0 conflicts measured): lane covers
  // row (lane>>3), chunk (lane&7) of an 8-row stripe; LDS dest linear;
  // global col chunk XOR-permuted so swizzled reads see logical k order.
  const int srow = lane >> 3;                       // 0..7
  const int scol = ((lane & 7) ^ srow) << 3;        // inverse-swizzled global col (elems)
  const bf16* gA = Ab + (size_t)(m0b + wave * 8 + srow) * lda + scol;
  const bf16* gB = Bb + (size_t)(n0b + wave * 8 + srow) * ldb + scol;
  const int lofs = wave * (8 * 64) + lane * 8;
  bf16* lA[2] = {&As[0][lofs], &As[1][lofs]};
  bf16* lB[2] = {&Bs[0][lofs], &Bs[1][lofs]};

  // ---- fragment read addressing (row&7 == fl&7 for all frag rows)
  const int fl = lane & 15, quad = lane >> 4;
  const int wm = (wave >> 2) * 64;                  // 2 wave-rows x 64
  const int wn = (wave & 3) * 32;                   // 4 wave-cols x 32
  const int ch0 = (quad ^ (fl & 7)) << 3;           // ks=0 chunk (elems); ks=1: ^32

  floatx4 acc[4][2];
#pragma unroll
  for (int mi = 0; mi < 4; ++mi)
#pragma unroll
    for (int ni = 0; ni < 2; ++ni) acc[mi][ni] = (floatx4){0.f, 0.f, 0.f, 0.f};

  // prologue: 2 K-tiles in flight (8 outstanding block-wide loads)
  {
    gl_lds16(gA, lA[0]);
    gl_lds16(gA + (size_t)64 * lda, lA[0] + 4096);
    gl_lds16(gB, lB[0]);
    gl_lds16(gB + (size_t)64 * ldb, lB[0] + 4096);
  }
  if (nkt > 1) {
    gl_lds16(gA + 64, lA[1]);
    gl_lds16(gA + (size_t)64 * lda + 64, lA[1] + 4096);
    gl_lds16(gB + 64, lB[1]);
    gl_lds16(gB + (size_t)64 * ldb + 64, lB[1] + 4096);
  }

  for (int kt = 0; kt < nkt; ++kt) {
    if (kt + 1 < nkt) {
      asm volatile("s_waitcnt vmcnt(4)" ::: "memory");   // tile kt landed; kt+1 in flight
    } else {
      asm volatile("s_waitcnt vmcnt(0)" ::: "memory");   // last tile: full drain
    }
    __builtin_amdgcn_s_barrier();
    __builtin_amdgcn_sched_barrier(0);

    const bf16* as = (kt & 1) ? &As[1][0] : &As[0][0];
    const bf16* bs = (kt & 1) ? &Bs[1][0] : &Bs[0][0];
#pragma unroll
    for (int ks = 0; ks < 2; ++ks) {
      const int ch = ch0 ^ (ks << 5);
      short8 af[4], bv[2];
#pragma unroll
      for (int mi = 0; mi < 4; ++mi)
        af[mi] = *reinterpret_cast<const short8*>(&as[(wm + mi * 16 + fl) * 64 + ch]);
#pragma unroll
      for (int ni = 0; ni < 2; ++ni)
        bv[ni] = *reinterpret_cast<const short8*>(&bs[(wn + ni * 16 + fl) * 64 + ch]);
      __builtin_amdgcn_s_setprio(1);
#pragma unroll
      for (int mi = 0; mi < 4; ++mi)
#pragma unroll
        for (int ni = 0; ni < 2; ++ni)
          acc[mi][ni] = __builtin_amdgcn_mfma_f32_16x16x32_bf16(af[mi], bv[ni], acc[mi][ni], 0, 0, 0);
      __builtin_amdgcn_s_setprio(0);
    }
    __builtin_amdgcn_sched_barrier(0);
    __builtin_amdgcn_s_barrier();     // all waves done reading buf[kt&1]
    if (kt + 2 < nkt) {
      const size_t ko = (size_t)(kt + 2) << 6;
      bf16* dA = (kt & 1) ? lA[1] : lA[0];
      bf16* dB = (kt & 1) ? lB[1] : lB[0];
      gl_lds16(gA + ko, dA);
      gl_lds16(gA + (size_t)64 * lda + ko, dA + 4096);
      gl_lds16(gB + ko, dB);
      gl_lds16(gB + (size_t)64 * ldb + ko, dB + 4096);
    }
  }

#pragma unroll
  for (int mi = 0; mi < 4; ++mi) {
#pragma unroll
    for (int r = 0; r < 4; ++r) {
      const int row = m0b + wm + mi * 16 + quad * 4 + r;
#pragma unroll
      for (int ni = 0; ni < 2; ++ni) {
        const int col = n0b + wn + ni * 16 + fl;
        float v = acc[mi][ni][r];
        if (bias) v += bias[col];
        if (act_gelu) v = 0.5f * v * (1.0f + erff(v * 0.70710678118654752f));
        const size_t idx = (size_t)row * N + col;
        if (of) of[idx] = v;
        else    ob[idx] = __float2bfloat16(v);
      }
    }
  }
}

// ---------------------------------------------------------------------------
// MFMA flash attention, fixed-base softmax (m == 0).
// Q fragments in registers; VT sigma row-permutation (conflict-free);
// R7: T14 async-STAGE split — tile jt+1's K/V/kr loads issued into registers
// BEFORE compute(jt); regs written to LDS after the next barrier. HBM/L2
// latency hides under the QK/softmax/PV compute of the current tile.
// ---------------------------------------------------------------------------
__global__ __launch_bounds__(256, 3) void attn_kernel(
    const bf16* __restrict__ qkv, const bf16* __restrict__ kr,
    const float* __restrict__ dsb, const float* __restrict__ seg_embed,
    const float* __restrict__ rwb, const float* __restrict__ rrb,
    const float* __restrict__ rsb,
    bf16* __restrict__ av_out)
{
  const int bx = blockIdx.x;
  const int n  = bx & 15;
  const int b  = (bx >> 4) & 3;
  const int it = 15 - (bx >> 6);     // heavy tiles first
  const int i0 = it * 64;
  const int tid = threadIdx.x;

  const bf16* qh = qkv + n * DH;
  const bf16* kh = qkv + ND + n * DH;
  const bf16* vh = qkv + 2 * ND + n * DH;

  __shared__ bf16 Kb[64][72];
  __shared__ bf16 VT[64][72];
  __shared__ bf16 krw[128][72];
  __shared__ bf16 bdrL[64][88];
  __shared__ float efs0[64], efs1[64];
  __shared__ float dsq[64], dsk[64];

  const int wave = tid >> 6, lane = tid & 63;
  const int fl = lane & 15, quad = lane >> 4;
  const int wq0 = wave * 16;
  const int tb0 = 3 - wave;
  const int twoc = (tid & 3) << 1;   // VT sigma: row XOR for this thread's d-block

  // ---- prologue: Q fragments in registers + ef sums ----
  short8 aw[2], ar[2];
  {
    const int qrow = i0 + wq0 + fl;
    const bf16* qp = qh + (size_t)(qrow * BB + b) * QKVS;
    float e0 = 0.f, e1 = 0.f;
#pragma unroll
    for (int ks = 0; ks < 2; ++ks) {
      const int d0 = ks * 32 + quad * 8;
      const uint4 qv = *reinterpret_cast<const uint4*>(qp + d0);
      const bf16* qe = reinterpret_cast<const bf16*>(&qv);
      bf16 wt[8], rt[8];
#pragma unroll
      for (int u = 0; u < 8; ++u) {
        const int d = d0 + u;
        const float qf = __bfloat162float(qe[u]);
        wt[u] = __float2bfloat16(qf + rwb[n * DH + d]);
        rt[u] = __float2bfloat16(qf + rrb[n * DH + d]);
        const float qs = qf + rsb[n * DH + d];
        e0 += qs * seg_embed[(0 * NH + n) * DH + d];
        e1 += qs * seg_embed[(1 * NH + n) * DH + d];
      }
      aw[ks] = *reinterpret_cast<short8*>(wt);
      ar[ks] = *reinterpret_cast<short8*>(rt);
    }
    // full-row sums live across the 4 quad-lanes of the same fl
    e0 += __shfl_xor(e0, 16, 64); e0 += __shfl_xor(e0, 32, 64);
    e1 += __shfl_xor(e1, 16, 64); e1 += __shfl_xor(e1, 32, 64);
    if (quad == 0) { efs0[wq0 + fl] = e0; efs1[wq0 + fl] = e1; }
    if (tid < 64) dsq[tid] = dsb[b * QLEN + i0 + tid];
  }

  floatx4 O[4];
#pragma unroll
  for (int nb = 0; nb < 4; ++nb) O[nb] = (floatx4){0.f, 0.f, 0.f, 0.f};
  float l_loc[4] = {0.f, 0.f, 0.f, 0.f};

  // ---- T14 prologue: tile-0 K/V/kr loads into registers ----
  const int sj  = tid >> 2;               // 0..63  (K/V row)
  const int sdc = (tid & 3) << 4;         // 0/16/32/48 (K/V d-chunk)
  const int st  = tid >> 1;               // 0..127 (kr row)
  const int sdc2= (tid & 1) << 5;         // 0/32   (kr d-chunk)
  uint4 kv0, kv1, vv0, vv1, rr0, rr1, rr2, rr3;
  {
    const bf16* kp = kh + (size_t)((0 + sj) * BB + b) * QKVS + sdc;
    kv0 = reinterpret_cast<const uint4*>(kp)[0];
    kv1 = reinterpret_cast<const uint4*>(kp)[1];
    const bf16* vp = vh + (size_t)((0 + sj) * BB + b) * QKVS + sdc;
    vv0 = reinterpret_cast<const uint4*>(vp)[0];
    vv1 = reinterpret_cast<const uint4*>(vp)[1];
    const int kbase0 = QLEN - i0 - 63;
    const bf16* rp = kr + ((size_t)((kbase0 + st) * BB + b)) * ND + n * DH + sdc2;
    rr0 = reinterpret_cast<const uint4*>(rp)[0];
    rr1 = reinterpret_cast<const uint4*>(rp)[1];
    rr2 = reinterpret_cast<const uint4*>(rp)[2];
    rr3 = reinterpret_cast<const uint4*>(rp)[3];
  }

  for (int jt = 0; jt <= it; ++jt) {
    const int j0 = jt * 64;

    __syncthreads();     // A: previous tile's LDS reads complete

    // ---- write prefetched registers -> LDS ----
    {
      reinterpret_cast<uint4*>(&Kb[sj][sdc])[0] = kv0;
      reinterpret_cast<uint4*>(&Kb[sj][sdc + 8])[0] = kv1;
      const bf16* ve0 = reinterpret_cast<const bf16*>(&vv0);
      const bf16* ve1 = reinterpret_cast<const bf16*>(&vv1);
#pragma unroll
      for (int u = 0; u < 8; ++u) {
        VT[sdc + (u ^ twoc)][sj] = ve0[u];
        VT[sdc + 8 + (u ^ twoc)][sj] = ve1[u];
      }
      reinterpret_cast<uint4*>(&krw[st][sdc2 + 0])[0]  = rr0;
      reinterpret_cast<uint4*>(&krw[st][sdc2 + 8])[0]  = rr1;
      reinterpret_cast<uint4*>(&krw[st][sdc2 + 16])[0] = rr2;
      reinterpret_cast<uint4*>(&krw[st][sdc2 + 24])[0] = rr3;
      if (tid < 64) dsk[tid] = dsb[b * QLEN + j0 + tid];
    }

    // ---- issue next tile's loads (land during this tile's compute) ----
    if (jt < it) {
      const int j0n = j0 + 64;
      const bf16* kp = kh + (size_t)((j0n + sj) * BB + b) * QKVS + sdc;
      kv0 = reinterpret_cast<const uint4*>(kp)[0];
      kv1 = reinterpret_cast<const uint4*>(kp)[1];
      const bf16* vp = vh + (size_t)((j0n + sj) * BB + b) * QKVS + sdc;
      vv0 = reinterpret_cast<const uint4*>(vp)[0];
      vv1 = reinterpret_cast<const uint4*>(vp)[1];
      const int kbn = QLEN + j0n - i0 - 63;
      const bf16* rp = kr + ((size_t)((kbn + st) * BB + b)) * ND + n * DH + sdc2;
      rr0 = reinterpret_cast<const uint4*>(rp)[0];
      rr1 = reinterpret_cast<const uint4*>(rp)[1];
      rr2 = reinterpret_cast<const uint4*>(rp)[2];
      rr3 = reinterpret_cast<const uint4*>(rp)[3];
    }

    __syncthreads();     // B: staged LDS visible to all waves

    floatx4 accS[4], accB[5];
#pragma unroll
    for (int nb = 0; nb < 4; ++nb) accS[nb] = (floatx4){0.f, 0.f, 0.f, 0.f};
#pragma unroll
    for (int u = 0; u < 5; ++u) accB[u] = (floatx4){0.f, 0.f, 0.f, 0.f};
#pragma unroll
    for (int ks = 0; ks < 2; ++ks) {
#pragma unroll
      for (int nb = 0; nb < 4; ++nb)
        accS[nb] = __builtin_amdgcn_mfma_f32_16x16x32_bf16(
            aw[ks], *reinterpret_cast<const short8*>(&Kb[nb * 16 + fl][ks * 32 + quad * 8]), accS[nb], 0, 0, 0);
#pragma unroll
      for (int u = 0; u < 5; ++u)
        accB[u] = __builtin_amdgcn_mfma_f32_16x16x32_bf16(
            ar[ks], *reinterpret_cast<const short8*>(&krw[(tb0 + u) * 16 + fl][ks * 32 + quad * 8]), accB[u], 0, 0, 0);
    }
#pragma unroll
    for (int u = 0; u < 5; ++u)
#pragma unroll
      for (int r = 0; r < 4; ++r)
        bdrL[wq0 + quad * 4 + r][u * 16 + fl] = __float2bfloat16(accB[u][r]);

    // ---- combine + mask + seg; fixed-base exp; P store ----
    float pv[4][4];
#pragma unroll
    for (int r = 0; r < 4; ++r) {
      const int qL = wq0 + quad * 4 + r;
      const int qg = i0 + qL;
      const float e0q = efs0[qL], e1q = efs1[qL];
      const float dq = dsq[qL];
#pragma unroll
      for (int nb = 0; nb < 4; ++nb) {
        const int kL = nb * 16 + fl;
        const int kg = j0 + kL;
        const float bdv = __bfloat162float(bdrL[qL][15 + kL - quad * 4 - r]);
        const float ef = (dq != dsk[kL]) ? e1q : e0q;
        const float s = (accS[nb][r] + bdv + ef) * SCALE;
        const float pe = (kg > qg) ? 0.0f : __expf(s);
        pv[nb][r] = pe;
        l_loc[r] += pe;
      }
    }

    // ---- P into own bdrL rows [0,64) (after all bdv reads; same wave) ----
#pragma unroll
    for (int nb = 0; nb < 4; ++nb)
#pragma unroll
      for (int r = 0; r < 4; ++r)
        bdrL[wq0 + quad * 4 + r][nb * 16 + fl] = __float2bfloat16(pv[nb][r]);

    // ---- PV MFMA: O[q][d] += P @ V  (VT rows sigma-permuted) ----
#pragma unroll
    for (int ks = 0; ks < 2; ++ks) {
      const short8 ap = *reinterpret_cast<const short8*>(&bdrL[wq0 + fl][ks * 32 + quad * 8]);
#pragma unroll
      for (int nb = 0; nb < 4; ++nb)
        O[nb] = __builtin_amdgcn_mfma_f32_16x16x32_bf16(
            ap, *reinterpret_cast<const short8*>(&VT[nb * 16 + (fl ^ (nb << 1))][ks * 32 + quad * 8]), O[nb], 0, 0, 0);
    }
  }

  // ---- epilogue: single l reduction (over fl lanes), normalize, store ----
  float inv[4];
#pragma unroll
  for (int r = 0; r < 4; ++r) {
    float l = l_loc[r];
    l += __shfl_xor(l, 1, 64);
    l += __shfl_xor(l, 2, 64);
    l += __shfl_xor(l, 4, 64);
    l += __shfl_xor(l, 8, 64);
    inv[r] = 1.0f / l;
  }
#pragma unroll
  for (int r = 0; r < 4; ++r) {
    const int qL = wq0 + quad * 4 + r;
    bf16* op = av_out + ((size_t)((i0 + qL) * BB + b)) * ND + n * DH;
#pragma unroll
    for (int nb = 0; nb < 4; ++nb)
      op[nb * 16 + fl] = __float2bfloat16(O[nb][r] * inv[r]);
  }
}

// ---------------------------------------------------------------------------
// LN1: x = pa + pb + resid; out = LN(x)*g + beta -> outf/outb.
// ---------------------------------------------------------------------------
__global__ __launch_bounds__(256) void ln_fused(
    const float* __restrict__ pa, const float* __restrict__ pb,
    const float* __restrict__ resid,
    const float* __restrict__ gg, const float* __restrict__ bbias,
    float* __restrict__ outf, bf16* __restrict__ outb)
{
  const int row = blockIdx.x;
  const int tid = threadIdx.x;
  __shared__ float red[4];
  const size_t base = (size_t)row * DMODEL;

  float v[4];
  float s = 0.0f;
#pragma unroll
  for (int k = 0; k < 4; ++k) {
    const int c = k * 256 + tid;
    const float x = pa[base + c] + pb[base + c] + resid[base + c];
    v[k] = x;
    s += x;
  }
#pragma unroll
  for (int off = 32; off; off >>= 1) s += __shfl_xor(s, off, 64);
  const int w = tid >> 6, lane = tid & 63;
  if (lane == 0) red[w] = s;
  __syncthreads();
  const float mean = (red[0] + red[1] + red[2] + red[3]) * (1.0f / DMODEL);

  float s2 = 0.0f;
#pragma unroll
  for (int k = 0; k < 4; ++k) {
    const float dlt = v[k] - mean;
    s2 += dlt * dlt;
  }
  __syncthreads();
#pragma unroll
  for (int off = 32; off; off >>= 1) s2 += __shfl_xor(s2, off, 64);
  if (lane == 0) red[w] = s2;
  __syncthreads();
  const float var = (red[0] + red[1] + red[2] + red[3]) * (1.0f / DMODEL);
  const float rstd = rsqrtf(var + 1e-12f);

#pragma unroll
  for (int k = 0; k < 4; ++k) {
    const int c = k * 256 + tid;
    const float o = (v[k] - mean) * rstd * gg[c] + bbias[c];
    if (outf) outf[base + c] = o;
    if (outb) outb[base + c] = __float2bfloat16(o);
  }
}

// ---------------------------------------------------------------------------
// LN2: x = pa+pb (bf16 partials) + resid + bias; out = LN(x)*g + beta.
// ---------------------------------------------------------------------------
__global__ __launch_bounds__(256) void ln_fused2b(
    const bf16* __restrict__ pa, const bf16* __restrict__ pb,
    const float* __restrict__ resid, const float* __restrict__ bias,
    const float* __restrict__ gg, const float* __restrict__ bbias,
    float* __restrict__ outf)
{
  const int row = blockIdx.x;
  const int tid = threadIdx.x;
  __shared__ float red[4];
  const size_t base = (size_t)row * DMODEL;

  float v[4];
  float s = 0.0f;
#pragma unroll
  for (int k = 0; k < 4; ++k) {
    const int c = k * 256 + tid;
    float x = __bfloat162float(pa[base + c]) + __bfloat162float(pb[base + c]) +
              resid[base + c] + bias[c];
    v[k] = x;
    s += x;
  }
#pragma unroll
  for (int off = 32; off; off >>= 1) s += __shfl_xor(s, off, 64);
  const int w = tid >> 6, lane = tid & 63;
  if (lane == 0) red[w] = s;
  __syncthreads();
  const float mean = (red[0] + red[1] + red[2] + red[3]) * (1.0f / DMODEL);

  float s2 = 0.0f;
#pragma unroll
  for (int k = 0; k < 4; ++k) {
    const float dlt = v[k] - mean;
    s2 += dlt * dlt;
  }
  __syncthreads();
#pragma unroll
  for (int off = 32; off; off >>= 1) s2 += __shfl_xor(s2, off, 64);
  if (lane == 0) red[w] = s2;
  __syncthreads();
  const float var = (red[0] + red[1] + red[2] + red[3]) * (1.0f / DMODEL);
  const float rstd = rsqrtf(var + 1e-12f);

#pragma unroll
  for (int k = 0; k < 4; ++k) {
    const int c = k * 256 + tid;
    outf[base + c] = (v[k] - mean) * rstd * gg[c] + bbias[c];
  }
}

// ---------------------------------------------------------------------------
extern "C" void kernel_launch(void* const* d_in, const int* in_sizes, int n_in,
                              void* d_out, int out_size, void* d_ws, size_t ws_size,
                              hipStream_t stream) {
  const float* h         = (const float*)d_in[0];
  const float* r         = (const float*)d_in[1];
  const float* seg_mat   = (const float*)d_in[3];
  const float* q_w       = (const float*)d_in[4];
  const float* k_w       = (const float*)d_in[5];
  const float* v_w       = (const float*)d_in[6];
  const float* o_w       = (const float*)d_in[7];
  const float* r_w       = (const float*)d_in[8];
  const float* r_r_bias  = (const float*)d_in[9];
  const float* r_s_bias  = (const float*)d_in[10];
  const float* r_w_bias  = (const float*)d_in[11];
  const float* seg_embed = (const float*)d_in[12];
  const float* ln1_g     = (const float*)d_in[13];
  const float* ln1_b     = (const float*)d_in[14];
  const float* ff_w1     = (const float*)d_in[15];
  const float* ff_b1     = (const float*)d_in[16];
  const float* ff_w2     = (const float*)d_in[17];
  const float* ff_b2     = (const float*)d_in[18];
  const float* ln2_g     = (const float*)d_in[19];
  const float* ln2_b     = (const float*)d_in[20];
  float* outp = (float*)d_out;

  const size_t M1 = (size_t)QLEN * BB;   // 4096
  const size_t MRU = (size_t)RUSED * BB; // 4608 (kr rows used)
  char* ws = (char*)d_ws;
  const size_t MB = 1u << 20;

  bf16* hb   = (bf16*)(ws + 0 * MB);     // 8 MB   [P0..P1]
  bf16* rb   = (bf16*)(ws + 8 * MB);     // 9 MB   [P0..P1]
  bf16* wqkvt= (bf16*)(ws + 24 * MB);    // 6 MB   [P0..P1]
  bf16* wrt  = (bf16*)(ws + 30 * MB);    // 2 MB   [P0..P1]
  bf16* wo   = (bf16*)(ws + 32 * MB);    // 2 MB   [P0..P3]
  bf16* w1t  = (bf16*)(ws + 34 * MB);    // 8 MB   [P0..P5]
  bf16* w2t  = (bf16*)(ws + 42 * MB);    // 8 MB   [P0..P6]
  bf16* qkvb = (bf16*)(ws + 50 * MB);    // 24 MB  [P1..P2]
  bf16* krb  = (bf16*)(ws + 74 * MB);    // 9 MB   [P1..P2]
  bf16* avb  = (bf16*)(ws + 90 * MB);    // 8 MB   [P2..P3]
  float* pa1  = (float*)(ws + 0 * MB);   // 16 MB [P3..P4] over hb/rb (dead)
  float* pb1  = (float*)(ws + 16 * MB);  // 16 MB [P3..P4] over rb tail+wqkvt+wrt (dead)
  float* out1 = (float*)(ws + 50 * MB);  // 16 MB [P4..P7] over qkvb (dead)
  bf16* out1b = (bf16*)(ws + 66 * MB);   // 8 MB  [P4..P5] over qkvb tail (dead)
  bf16* ff1   = (bf16*)(ws + 0 * MB);    // 32 MB [P5..P6] over pa1/pb1 (dead)
  bf16* p2    = (bf16*)(ws + 74 * MB);   // 2x8 MB [P6..P7] over krb+avb (dead): 74/82
  float* dsbuf = (float*)(ws + 106 * MB); // 16 KB [P0..P2]

  dim3 blk(256);
  dim3 blk512(512);

  // P0: fused conversions (r only first RUSED rows)
  cvt_all<<<dim3(4864), blk, 0, stream>>>(h, r, o_w, hb, rb, wo);
  tconv_all<<<dim3(12288), blk, 0, stream>>>(q_w, k_w, v_w, r_w, ff_w1, ff_w2,
                                             wqkvt, wrt, w1t, w2t);
  seg_extract<<<dim3(16), blk, 0, stream>>>(seg_mat, dsbuf);

  // P1: qkv (N=3072) + kr (M=4608), both on gemm256 counted-vmcnt
  gemm256<<<dim3(QKVS / 128, M1 / 128, 1), blk512, 0, stream>>>(
      hb, wqkvt, (int)M1, QKVS, DMODEL, DMODEL, DMODEL, DMODEL, nullptr, 0, nullptr, qkvb, 0);
  gemm256<<<dim3(ND / 128, (int)(MRU / 128), 1), blk512, 0, stream>>>(
      rb, wrt, (int)MRU, ND, DMODEL, DMODEL, DMODEL, DMODEL, nullptr, 0, nullptr, krb, 0);

  // P2: fused relative attention (MFMA, fixed-base softmax, T14 prefetch)
  attn_kernel<<<dim3(16 * BB * NH), blk, 0, stream>>>(
      qkvb, krb, dsbuf, seg_embed,
      r_w_bias, r_r_bias, r_s_bias, avb);

  // P3: output projection, split-K=2 -> raw f32 partials pa1/pb1 (gemm256)
  gemm256<<<dim3(DMODEL / 128, M1 / 128, 2), blk512, 0, stream>>>(
      avb, wo, (int)M1, DMODEL, ND / 2, ND, ND, ND, nullptr, 0, pa1, nullptr, (int)(M1 * DMODEL));

  // P4: LN1( pa1 + pb1 + h ) -> out1 f32 + out1b bf16
  ln_fused<<<dim3((int)M1), blk, 0, stream>>>(pa1, pb1, h, ln1_g, ln1_b, out1, out1b);

  // P5: FF1 gelu(out1@W1+b1) -> bf16, gemm256
  gemm256<<<dim3(DI / 128, M1 / 128, 1), blk512, 0, stream>>>(
      out1b, w1t, (int)M1, DI, DMODEL, DMODEL, DMODEL, DMODEL, ff_b1, 1, nullptr, ff1, 0);

  // P6: FF2 split-K=2 (K=2048 each) -> bf16 partials p2[0..1], gemm256
  gemm256<<<dim3(DMODEL / 128, M1 / 128, 2), blk512, 0, stream>>>(
      ff1, w2t, (int)M1, DMODEL, DI / 2, DI, DI, DI, nullptr, 0, nullptr, p2, (int)(M1 * DMODEL));

  // P7: LN2( p2[0..1] + b2 + out1 ) -> d_out
  ln_fused2b<<<dim3((int)M1), blk, 0, stream>>>(
      p2, p2 + M1 * DMODEL,
      out1, ff_b2, ln2_g, ln2_b, outp);
}